// Round 1
// baseline (74714.325 us; speedup 1.0000x reference)
//
#include <hip/hip_runtime.h>
#include <math.h>

#define BATCH 8
#define SEQ   2048
#define IN    8
#define HID   256
#define G4    1024   // 4*HID

__device__ __forceinline__ float sigmoidf_(float x) { return 1.0f / (1.0f + expf(-x)); }

// ---------------------------------------------------------------------------
// LSTM layer 0: input proj (I=8) fused into the recurrence.
// One block (1024 threads) per batch element. Thread t owns gate-row t of
// w_hh in 256 VGPRs. h broadcast via LDS (wave-uniform ds_read_b128).
// ---------------------------------------------------------------------------
__global__ __launch_bounds__(1024) void lstm0_kernel(
    const float* __restrict__ x,      // [B][S][8]
    const float* __restrict__ w_ih,   // [1024][8]
    const float* __restrict__ w_hh,   // [1024][256]
    const float* __restrict__ b_ih,   // [1024]
    const float* __restrict__ b_hh,   // [1024]
    float* __restrict__ h_out)        // [B][S][256]
{
    const int b = blockIdx.x;
    const int t = threadIdx.x;

    float w[256];
    {
        const float4* wr = (const float4*)(w_hh + (size_t)t * HID);
#pragma unroll
        for (int k = 0; k < 64; k++) {
            float4 v = wr[k];
            w[4*k+0] = v.x; w[4*k+1] = v.y; w[4*k+2] = v.z; w[4*k+3] = v.w;
        }
    }
    float wi[IN];
    {
        const float* wir = w_ih + (size_t)t * IN;
#pragma unroll
        for (int k = 0; k < IN; k++) wi[k] = wir[k];
    }
    const float bias = b_ih[t] + b_hh[t];

    __shared__ __align__(16) float h_lds[HID];
    __shared__ float g_lds[G4];
    float c = 0.0f;
    if (t < HID) h_lds[t] = 0.0f;

    const float* xb = x + (size_t)b * SEQ * IN;
    float* ho = h_out + (size_t)b * SEQ * HID;

    float4 x0 = *(const float4*)(xb + 0);
    float4 x1 = *(const float4*)(xb + 4);
    __syncthreads();

    for (int s = 0; s < SEQ; s++) {
        // prefetch next step's x (hides HBM latency behind the FMA loop)
        float4 x0n = x0, x1n = x1;
        if (s + 1 < SEQ) {
            x0n = *(const float4*)(xb + (size_t)(s + 1) * IN);
            x1n = *(const float4*)(xb + (size_t)(s + 1) * IN + 4);
        }
        float a0 = bias + wi[0]*x0.x + wi[1]*x0.y + wi[2]*x0.z + wi[3]*x0.w;
        float a1 =        wi[4]*x1.x + wi[5]*x1.y + wi[6]*x1.z + wi[7]*x1.w;
        float a2 = 0.0f, a3 = 0.0f;
#pragma unroll
        for (int k = 0; k < 64; k++) {
            float4 h4 = ((const float4*)h_lds)[k];   // broadcast read
            a0 += w[4*k+0] * h4.x;
            a1 += w[4*k+1] * h4.y;
            a2 += w[4*k+2] * h4.z;
            a3 += w[4*k+3] * h4.w;
        }
        g_lds[t] = (a0 + a2) + (a1 + a3);
        __syncthreads();
        if (t < HID) {
            float iv = sigmoidf_(g_lds[t]);
            float fv = sigmoidf_(g_lds[t + 256]);
            float gv = tanhf(g_lds[t + 512]);
            float ov = sigmoidf_(g_lds[t + 768]);
            c = fv * c + iv * gv;
            float h = ov * tanhf(c);
            h_lds[t] = h;
            ho[(size_t)s * HID + t] = h;
        }
        __syncthreads();
        x0 = x0n; x1 = x1n;
    }
}

// ---------------------------------------------------------------------------
// LSTM recurrence with precomputed x_proj (layer 1).
// ---------------------------------------------------------------------------
__global__ __launch_bounds__(1024) void lstm_rec_kernel(
    const float* __restrict__ xproj,  // [B][S][1024] (biases already added)
    const float* __restrict__ w_hh,   // [1024][256]
    float* __restrict__ h_out)        // [B][S][256]
{
    const int b = blockIdx.x;
    const int t = threadIdx.x;

    float w[256];
    {
        const float4* wr = (const float4*)(w_hh + (size_t)t * HID);
#pragma unroll
        for (int k = 0; k < 64; k++) {
            float4 v = wr[k];
            w[4*k+0] = v.x; w[4*k+1] = v.y; w[4*k+2] = v.z; w[4*k+3] = v.w;
        }
    }

    __shared__ __align__(16) float h_lds[HID];
    __shared__ float g_lds[G4];
    float c = 0.0f;
    if (t < HID) h_lds[t] = 0.0f;

    const float* xp = xproj + (size_t)b * SEQ * G4;
    float* ho = h_out + (size_t)b * SEQ * HID;

    float xv = xp[t];
    __syncthreads();

    for (int s = 0; s < SEQ; s++) {
        float xn = xv;
        if (s + 1 < SEQ) xn = xp[(size_t)(s + 1) * G4 + t];
        float a0 = xv, a1 = 0.0f, a2 = 0.0f, a3 = 0.0f;
#pragma unroll
        for (int k = 0; k < 64; k++) {
            float4 h4 = ((const float4*)h_lds)[k];
            a0 += w[4*k+0] * h4.x;
            a1 += w[4*k+1] * h4.y;
            a2 += w[4*k+2] * h4.z;
            a3 += w[4*k+3] * h4.w;
        }
        g_lds[t] = (a0 + a2) + (a1 + a3);
        __syncthreads();
        if (t < HID) {
            float iv = sigmoidf_(g_lds[t]);
            float fv = sigmoidf_(g_lds[t + 256]);
            float gv = tanhf(g_lds[t + 512]);
            float ov = sigmoidf_(g_lds[t + 768]);
            c = fv * c + iv * gv;
            float h = ov * tanhf(c);
            h_lds[t] = h;
            ho[(size_t)s * HID + t] = h;
        }
        __syncthreads();
        xv = xn;
    }
}

// ---------------------------------------------------------------------------
// NT GEMM: C[M][N] = A[M][K] @ W[N][K]^T + bias1 (+ bias2). 64x64x16 tiles,
// 256 threads, 4x4 micro-tile.
// ---------------------------------------------------------------------------
__global__ __launch_bounds__(256) void gemm_nt_bias(
    const float* __restrict__ A, const float* __restrict__ W,
    const float* __restrict__ bias1, const float* __restrict__ bias2,
    float* __restrict__ C, int M, int N, int K)
{
    __shared__ __align__(16) float As[16][68];  // +4 pad: no 4-way write conflicts
    __shared__ __align__(16) float Bs[16][68];
    const int tid = threadIdx.x;
    const int tx = tid & 15;          // col group
    const int ty = tid >> 4;          // row group
    const int bm = blockIdx.x * 64;
    const int bn = blockIdx.y * 64;
    const int lrow = tid >> 2;        // 0..63
    const int lk   = (tid & 3) * 4;   // 0,4,8,12

    float acc[4][4] = {};

    for (int k0 = 0; k0 < K; k0 += 16) {
        float4 a4 = *(const float4*)(A + (size_t)(bm + lrow) * K + k0 + lk);
        float4 b4 = *(const float4*)(W + (size_t)(bn + lrow) * K + k0 + lk);
        __syncthreads();   // protect previous tile's reads
        As[lk+0][lrow] = a4.x; As[lk+1][lrow] = a4.y; As[lk+2][lrow] = a4.z; As[lk+3][lrow] = a4.w;
        Bs[lk+0][lrow] = b4.x; Bs[lk+1][lrow] = b4.y; Bs[lk+2][lrow] = b4.z; Bs[lk+3][lrow] = b4.w;
        __syncthreads();
#pragma unroll
        for (int k = 0; k < 16; k++) {
            float4 av = *(const float4*)(&As[k][ty * 4]);
            float4 bv = *(const float4*)(&Bs[k][tx * 4]);
            acc[0][0] += av.x*bv.x; acc[0][1] += av.x*bv.y; acc[0][2] += av.x*bv.z; acc[0][3] += av.x*bv.w;
            acc[1][0] += av.y*bv.x; acc[1][1] += av.y*bv.y; acc[1][2] += av.y*bv.z; acc[1][3] += av.y*bv.w;
            acc[2][0] += av.z*bv.x; acc[2][1] += av.z*bv.y; acc[2][2] += av.z*bv.z; acc[2][3] += av.z*bv.w;
            acc[3][0] += av.w*bv.x; acc[3][1] += av.w*bv.y; acc[3][2] += av.w*bv.z; acc[3][3] += av.w*bv.w;
        }
    }

    const int col = bn + tx * 4;
    float4 bb = *(const float4*)(bias1 + col);
    if (bias2) {
        float4 b2 = *(const float4*)(bias2 + col);
        bb.x += b2.x; bb.y += b2.y; bb.z += b2.z; bb.w += b2.w;
    }
#pragma unroll
    for (int i = 0; i < 4; i++) {
        const int row = bm + ty * 4 + i;
        float4 o;
        o.x = acc[i][0] + bb.x; o.y = acc[i][1] + bb.y;
        o.z = acc[i][2] + bb.z; o.w = acc[i][3] + bb.w;
        *(float4*)(C + (size_t)row * N + col) = o;
    }
}

// ---------------------------------------------------------------------------
// Q projection at the last position only: q[b][:] = h1[b][S-1][:] @ wq^T + bq
// ---------------------------------------------------------------------------
__global__ __launch_bounds__(256) void qlast_kernel(
    const float* __restrict__ h1, const float* __restrict__ wq,
    const float* __restrict__ bq, float* __restrict__ qout)
{
    const int b = blockIdx.x;
    const int t = threadIdx.x;
    __shared__ __align__(16) float hs[HID];
    hs[t] = h1[((size_t)b * SEQ + (SEQ - 1)) * HID + t];
    __syncthreads();
    const float4* wr = (const float4*)(wq + (size_t)t * HID);
    float acc = 0.0f;
#pragma unroll
    for (int k = 0; k < 64; k++) {
        float4 wv = wr[k];
        float4 hv = ((const float4*)hs)[k];
        acc += wv.x*hv.x + wv.y*hv.y + wv.z*hv.z + wv.w*hv.w;
    }
    qout[b * HID + t] = acc + bq[t];
}

// ---------------------------------------------------------------------------
// Decode attention at query position S-1, with multiplicative decay on scores.
// One block per (batch, head). probs = softmax(q.k/8 * 0.95^(S-1-k)); out = p@V.
// ---------------------------------------------------------------------------
__global__ __launch_bounds__(256) void attn_kernel(
    const float* __restrict__ Kb,   // [B][S][256]
    const float* __restrict__ Vb,   // [B][S][256]
    const float* __restrict__ q,    // [B][256]
    float* __restrict__ attn)       // [B][256]
{
    const int b = blockIdx.x >> 2;
    const int h = blockIdx.x & 3;
    const int tid = threadIdx.x;

    __shared__ __align__(16) float qs[64];
    __shared__ float sc[SEQ];
    __shared__ float red[256];
    __shared__ float part[4][64];

    if (tid < 64) qs[tid] = q[b * HID + h * 64 + tid];
    __syncthreads();

    const float LN095 = -0.051293294387550533f;  // ln(0.95)
    for (int k = tid; k < SEQ; k += 256) {
        const float4* kr = (const float4*)(Kb + ((size_t)b * SEQ + k) * HID + h * 64);
        float acc = 0.0f;
#pragma unroll
        for (int d = 0; d < 16; d++) {
            float4 kv = kr[d];
            float4 qv = ((const float4*)qs)[d];
            acc += kv.x*qv.x + kv.y*qv.y + kv.z*qv.z + kv.w*qv.w;
        }
        float dec = expf(LN095 * (float)(SEQ - 1 - k));
        sc[k] = acc * 0.125f * dec;
    }
    __syncthreads();

    // max reduce
    float m = -INFINITY;
    for (int k = tid; k < SEQ; k += 256) m = fmaxf(m, sc[k]);
    red[tid] = m;
    for (int off = 128; off > 0; off >>= 1) {
        __syncthreads();
        if (tid < off) red[tid] = fmaxf(red[tid], red[tid + off]);
    }
    __syncthreads();
    const float mx = red[0];

    // exp + sum reduce
    float local = 0.0f;
    for (int k = tid; k < SEQ; k += 256) {
        float p = expf(sc[k] - mx);
        sc[k] = p;
        local += p;
    }
    __syncthreads();      // everyone has read red[0]
    red[tid] = local;
    for (int off = 128; off > 0; off >>= 1) {
        __syncthreads();
        if (tid < off) red[tid] += red[tid + off];
    }
    __syncthreads();
    const float total = red[0];

    // weighted V: 4 key-chunks x 64 dims
    const int chunk = tid >> 6;   // 0..3
    const int d = tid & 63;
    float acc = 0.0f;
    const int k0 = chunk * (SEQ / 4), k1 = (chunk + 1) * (SEQ / 4);
    for (int k = k0; k < k1; k++)
        acc += sc[k] * Vb[((size_t)b * SEQ + k) * HID + h * 64 + d];
    part[chunk][d] = acc;
    __syncthreads();
    if (tid < 64) {
        float r = (part[0][tid] + part[1][tid]) + (part[2][tid] + part[3][tid]);
        attn[b * HID + h * 64 + tid] = r / total;
    }
}

// ---------------------------------------------------------------------------
// Head: context = attn @ wo^T + bo ; mean/log_var = context @ w^T + b (5 each)
// d_out = [mean (8x5) | log_var (8x5)] fp32.
// ---------------------------------------------------------------------------
__global__ __launch_bounds__(256) void head_kernel(
    const float* __restrict__ attn, const float* __restrict__ wo,
    const float* __restrict__ bo, const float* __restrict__ w_mean,
    const float* __restrict__ b_mean, const float* __restrict__ w_var,
    const float* __restrict__ b_var, float* __restrict__ out)
{
    const int b = blockIdx.x;
    const int t = threadIdx.x;
    __shared__ __align__(16) float av[HID];
    __shared__ __align__(16) float ctx[HID];
    av[t] = attn[b * HID + t];
    __syncthreads();
    {
        const float4* wr = (const float4*)(wo + (size_t)t * HID);
        float acc = 0.0f;
#pragma unroll
        for (int k = 0; k < 64; k++) {
            float4 wv = wr[k];
            float4 hv = ((const float4*)av)[k];
            acc += wv.x*hv.x + wv.y*hv.y + wv.z*hv.z + wv.w*hv.w;
        }
        ctx[t] = acc + bo[t];
    }
    __syncthreads();
    if (t < 5) {
        const float4* wr = (const float4*)(w_mean + (size_t)t * HID);
        float acc = 0.0f;
#pragma unroll
        for (int k = 0; k < 64; k++) {
            float4 wv = wr[k];
            float4 hv = ((const float4*)ctx)[k];
            acc += wv.x*hv.x + wv.y*hv.y + wv.z*hv.z + wv.w*hv.w;
        }
        out[b * 5 + t] = acc + b_mean[t];
    } else if (t >= 8 && t < 13) {
        const int m = t - 8;
        const float4* wr = (const float4*)(w_var + (size_t)m * HID);
        float acc = 0.0f;
#pragma unroll
        for (int k = 0; k < 64; k++) {
            float4 wv = wr[k];
            float4 hv = ((const float4*)ctx)[k];
            acc += wv.x*hv.x + wv.y*hv.y + wv.z*hv.z + wv.w*hv.w;
        }
        out[BATCH * 5 + b * 5 + m] = acc + b_var[m];
    }
}

// ---------------------------------------------------------------------------
extern "C" void kernel_launch(void* const* d_in, const int* in_sizes, int n_in,
                              void* d_out, int out_size, void* d_ws, size_t ws_size,
                              hipStream_t stream) {
    const float* x      = (const float*)d_in[0];
    const float* w_ih0  = (const float*)d_in[1];
    const float* w_hh0  = (const float*)d_in[2];
    const float* b_ih0  = (const float*)d_in[3];
    const float* b_hh0  = (const float*)d_in[4];
    const float* w_ih1  = (const float*)d_in[5];
    const float* w_hh1  = (const float*)d_in[6];
    const float* b_ih1  = (const float*)d_in[7];
    const float* b_hh1  = (const float*)d_in[8];
    const float* wq     = (const float*)d_in[9];
    const float* bq     = (const float*)d_in[10];
    const float* wk     = (const float*)d_in[11];
    const float* bk     = (const float*)d_in[12];
    const float* wv     = (const float*)d_in[13];
    const float* bv     = (const float*)d_in[14];
    const float* wo     = (const float*)d_in[15];
    const float* bo     = (const float*)d_in[16];
    const float* w_mean = (const float*)d_in[17];
    const float* b_mean = (const float*)d_in[18];
    const float* w_var  = (const float*)d_in[19];
    const float* b_var  = (const float*)d_in[20];
    float* out = (float*)d_out;

    // Workspace layout (floats). Peak: 64 MiB (xproj) + 16 MiB (h) = 80 MiB.
    //  big region [0 .. 16.7M): xproj1; after lstm1 reused as K | V | q | attn
    //  hbuf [16.7M .. 20.9M): h0, then h1 (h0 dead after xproj1 GEMM)
    float* wsf   = (float*)d_ws;
    float* xproj = wsf;                               // 16384*1024 floats
    float* hbuf  = wsf + (size_t)16384 * 1024;        // 16384*256 floats
    float* Kbuf  = xproj;                             // 16384*256
    float* Vbuf  = xproj + (size_t)16384 * 256;       // 16384*256
    float* qbuf  = xproj + (size_t)2 * 16384 * 256;   // 8*256
    float* abuf  = qbuf + BATCH * HID;                // 8*256

    const int M = BATCH * SEQ;  // 16384

    // 1. LSTM layer 0 (fused input proj), h0 -> hbuf
    lstm0_kernel<<<BATCH, 1024, 0, stream>>>(x, w_ih0, w_hh0, b_ih0, b_hh0, hbuf);
    // 2. x_proj1 = h0 @ w_ih1^T + b_ih1 + b_hh1
    gemm_nt_bias<<<dim3(M / 64, G4 / 64), 256, 0, stream>>>(hbuf, w_ih1, b_ih1, b_hh1, xproj, M, G4, HID);
    // 3. LSTM layer 1 recurrence, h1 -> hbuf (overwrites h0; GEMM already consumed it)
    lstm_rec_kernel<<<BATCH, 1024, 0, stream>>>(xproj, w_hh1, hbuf);
    // 4. K, V projections (over the dead xproj region)
    gemm_nt_bias<<<dim3(M / 64, HID / 64), 256, 0, stream>>>(hbuf, wk, bk, nullptr, Kbuf, M, HID, HID);
    gemm_nt_bias<<<dim3(M / 64, HID / 64), 256, 0, stream>>>(hbuf, wv, bv, nullptr, Vbuf, M, HID, HID);
    // 5. Q at last position only
    qlast_kernel<<<BATCH, 256, 0, stream>>>(hbuf, wq, bq, qbuf);
    // 6. decode attention with decay
    attn_kernel<<<BATCH * 4, 256, 0, stream>>>(Kbuf, Vbuf, qbuf, abuf);
    // 7. output proj + gaussian head
    head_kernel<<<BATCH, 256, 0, stream>>>(abuf, wo, bo, w_mean, b_mean, w_var, b_var, out);
}

// Round 2
// 20821.545 us; speedup vs baseline: 3.5883x; 3.5883x over previous
//
#include <hip/hip_runtime.h>
#include <math.h>

#define BATCH 8
#define SEQ   2048
#define IN    8
#define HID   256
#define G4    1024   // 4*HID

typedef unsigned long long u64;
typedef unsigned int u32;

__device__ __forceinline__ float sigmoidf_(float x) { return 1.0f / (1.0f + __expf(-x)); }
__device__ __forceinline__ float tanhf_(float x) { return 1.0f - 2.0f / (__expf(2.0f * x) + 1.0f); }
// padded LDS index for h: +4 words per 32 to kill 8-way bank aliasing
__device__ __forceinline__ int hpad(int k) { return k + 4 * (k >> 5); }

// ---------------------------------------------------------------------------
// Multi-block LSTM recurrence. 4 blocks per batch (grid=32: b=idx&7, q=idx>>3
// so a batch's blocks {b,b+8,b+16,b+24} land on one XCD if dispatch is
// round-robin — speed heuristic only). Block owns units [64q,64q+64) = gate
// rows {256j+64q+rg}. Thread (rg=t>>3, ks=t&7) holds 4 rows x 32-K weight
// slice in 128 VGPRs (fits 256-VGPR budget at 512thr/2waves-per-EU -> no
// scratch spill, the R1 killer).
// Cross-block h exchange: tagged u64 slots {tag<<32 | h_bits}, device-scope
// atomics, parity double-buffer. Slots overlay dead ws rows:
//   even tags -> xp row (b,2047) floats [0,512)   (j0/j1 values preloaded)
//   odd  tags -> h_out rows (b,2046..2048)        (real h written at exit)
// Invariants (proven): publish-before-poll => no deadlock; a parity slot is
// only overwritten (tag+2) after every peer consumed tag => '!=tag' spin is
// exact; tag-2048 exit handshake orders the final h_out row stores after all
// peers' odd polls.
// MODE 0: layer0, input proj (K=8) fused. MODE 1: layer1, reads xp[B][S][1024].
// ---------------------------------------------------------------------------
template<int MODE>
__global__ __launch_bounds__(512, 2) void lstm_mb(
    const float* __restrict__ xin,    // MODE0: x [B][S][8]; MODE1: xp [B][S][1024]
    const float* __restrict__ w_hh,   // [1024][256]
    const float* __restrict__ w_ih,   // MODE0: [1024][8]
    const float* __restrict__ b_ih,   // MODE0
    const float* __restrict__ b_hh,   // MODE0
    float* __restrict__ scratch,      // xproj region base (even-slot host)
    float* __restrict__ h_out)        // [B][S][256]
{
    const int b  = blockIdx.x & 7;
    const int q  = blockIdx.x >> 3;
    const int t  = threadIdx.x;
    const int ks = t & 7;          // K-slice 0..7 (32 floats each)
    const int rg = t >> 3;         // unit-local 0..63
    const int wv = t >> 6;         // wave 0..7
    const int lane = t & 63;
    const bool isg = (ks == 0);    // gate/nonlinearity lanes

    // ---- per-thread weights: rows G_j = 256j + 64q + rg, cols [32ks,32ks+32)
    float4 w4[4][8];
#pragma unroll
    for (int j = 0; j < 4; j++) {
        const float4* wr = (const float4*)(w_hh + ((size_t)(256 * j + 64 * q + rg)) * HID + ks * 32);
#pragma unroll
        for (int i = 0; i < 8; i++) w4[j][i] = wr[i];
    }

    // MODE0: input-proj weights + bias; MODE1: preload j0/j1 of xp row 2047
    float4 wi[4][2];
    float bs[4];
    float xpl0 = 0.0f, xpl1 = 0.0f;
    if constexpr (MODE == 0) {
#pragma unroll
        for (int j = 0; j < 4; j++) {
            const int G = 256 * j + 64 * q + rg;
            wi[j][0] = *(const float4*)(w_ih + (size_t)G * IN);
            wi[j][1] = *(const float4*)(w_ih + (size_t)G * IN + 4);
            bs[j] = b_ih[G] + b_hh[G];
        }
    } else {
        const float* xl = xin + ((size_t)b * SEQ + (SEQ - 1)) * G4;
        xpl0 = xl[64 * q + rg];
        xpl1 = xl[256 + 64 * q + rg];
    }

    // slot areas
    u64* se = (u64*)(scratch + ((size_t)b * SEQ + (SEQ - 1)) * G4);   // even tags
    u64* so = (u64*)(h_out + ((size_t)b * SEQ + (SEQ - 2)) * HID);    // odd tags (2 rows = 256 u64)

    __shared__ float h_lds[284];
    for (int i = t; i < 284; i += 512) h_lds[i] = 0.0f;
    __syncthreads();

    float c = 0.0f, h46 = 0.0f, h47 = 0.0f;
    const float* xb = (MODE == 0) ? (xin + (size_t)b * SEQ * IN) : (xin + (size_t)b * SEQ * G4);
    float* ho = h_out + (size_t)b * SEQ * HID;

    for (int s = 0; s < SEQ; s++) {
        // ---- prefetch / compute input contribution (gate lanes)
        float xv0 = 0.0f, xv1 = 0.0f, xv2 = 0.0f, xv3 = 0.0f;
        if (isg) {
            if constexpr (MODE == 0) {
                const float4 xa = *(const float4*)(xb + (size_t)s * IN);
                const float4 xc = *(const float4*)(xb + (size_t)s * IN + 4);
                xv0 = bs[0] + wi[0][0].x*xa.x + wi[0][0].y*xa.y + wi[0][0].z*xa.z + wi[0][0].w*xa.w
                            + wi[0][1].x*xc.x + wi[0][1].y*xc.y + wi[0][1].z*xc.z + wi[0][1].w*xc.w;
                xv1 = bs[1] + wi[1][0].x*xa.x + wi[1][0].y*xa.y + wi[1][0].z*xa.z + wi[1][0].w*xa.w
                            + wi[1][1].x*xc.x + wi[1][1].y*xc.y + wi[1][1].z*xc.z + wi[1][1].w*xc.w;
                xv2 = bs[2] + wi[2][0].x*xa.x + wi[2][0].y*xa.y + wi[2][0].z*xa.z + wi[2][0].w*xa.w
                            + wi[2][1].x*xc.x + wi[2][1].y*xc.y + wi[2][1].z*xc.z + wi[2][1].w*xc.w;
                xv3 = bs[3] + wi[3][0].x*xa.x + wi[3][0].y*xa.y + wi[3][0].z*xa.z + wi[3][0].w*xa.w
                            + wi[3][1].x*xc.x + wi[3][1].y*xc.y + wi[3][1].z*xc.z + wi[3][1].w*xc.w;
            } else {
                if (s < SEQ - 1) {
                    const float* xr = xb + (size_t)s * G4 + 64 * q + rg;
                    xv0 = xr[0]; xv1 = xr[256]; xv2 = xr[512]; xv3 = xr[768];
                } else {
                    const float* xr = xb + (size_t)s * G4 + 64 * q + rg;
                    xv0 = xpl0; xv1 = xpl1;          // area overlaid by even slots
                    xv2 = xr[512]; xv3 = xr[768];    // [512,1024) never clobbered
                }
            }
        }

        // ---- matvec partials over own K-slice (conflict-free broadcast reads)
        float a0 = 0.0f, a1 = 0.0f, a2 = 0.0f, a3 = 0.0f;
#pragma unroll
        for (int i = 0; i < 8; i++) {
            const float4 h4 = *(const float4*)(&h_lds[36 * ks + 4 * i]);
            a0 += w4[0][i].x*h4.x + w4[0][i].y*h4.y + w4[0][i].z*h4.z + w4[0][i].w*h4.w;
            a1 += w4[1][i].x*h4.x + w4[1][i].y*h4.y + w4[1][i].z*h4.z + w4[1][i].w*h4.w;
            a2 += w4[2][i].x*h4.x + w4[2][i].y*h4.y + w4[2][i].z*h4.z + w4[2][i].w*h4.w;
            a3 += w4[3][i].x*h4.x + w4[3][i].y*h4.y + w4[3][i].z*h4.z + w4[3][i].w*h4.w;
        }
        __syncthreads();   // A: all h_lds reads of step s complete

        // ---- butterfly reduce across the 8 K-slices (lane bits 0..2)
#pragma unroll
        for (int m = 1; m <= 4; m <<= 1) {
            a0 += __shfl_xor(a0, m);
            a1 += __shfl_xor(a1, m);
            a2 += __shfl_xor(a2, m);
            a3 += __shfl_xor(a3, m);
        }

        const u32 tag = (u32)(s + 1);
        u64* sl = (tag & 1u) ? so : se;

        if (isg) {
            const float iv = sigmoidf_(a0 + xv0);
            const float fv = sigmoidf_(a1 + xv1);
            const float gv = tanhf_(a2 + xv2);
            const float ov = sigmoidf_(a3 + xv3);
            c = fv * c + iv * gv;
            const float hv = ov * tanhf_(c);
            const int u = 64 * q + rg;
            h_lds[hpad(u)] = hv;
            if (s == SEQ - 2)      h46 = hv;     // rows 2046/2047 are odd-slot area:
            else if (s == SEQ - 1) h47 = hv;     // stored after exit handshake
            else                   ho[(size_t)s * HID + u] = hv;
            const u64 pk = ((u64)tag << 32) | (u64)__float_as_uint(hv);
            __hip_atomic_store(&sl[u], pk, __ATOMIC_RELEASE, __HIP_MEMORY_SCOPE_AGENT);
        }
        // waves 1..3: fetch the 3 foreign 64-unit chunks (publish-before-poll)
        if (wv >= 1 && wv <= 3) {
            const int f = (q + wv) & 3;
            const int u = 64 * f + lane;
            u64* sp = &sl[u];
            u64 v;
            do {
                v = __hip_atomic_load(sp, __ATOMIC_ACQUIRE, __HIP_MEMORY_SCOPE_AGENT);
            } while ((u32)(v >> 32) != tag);
            h_lds[hpad(u)] = __uint_as_float((u32)v);
        }
        __syncthreads();   // B: h_{s+1} fully assembled
    }

    // exit: tag-2048 handshake passed => every peer finished its odd polls =>
    // safe to overwrite the odd-slot rows with the real final h values.
    if (isg) {
        const int u = 64 * q + rg;
        ho[(size_t)(SEQ - 2) * HID + u] = h46;
        ho[(size_t)(SEQ - 1) * HID + u] = h47;
    }
}

// ---------------------------------------------------------------------------
// NT GEMM: C[M][N] = A[M][K] @ W[N][K]^T + bias1 (+bias2). 128x128x16 tiles,
// 256 threads, 8x8 micro-tile (split 4+4 to keep LDS reads 2-way max).
// ---------------------------------------------------------------------------
__global__ __launch_bounds__(256) void gemm_nt_bias(
    const float* __restrict__ A, const float* __restrict__ W,
    const float* __restrict__ bias1, const float* __restrict__ bias2,
    float* __restrict__ C, int M, int N, int K)
{
    __shared__ float As[16][132];
    __shared__ float Bs[16][132];
    const int tid = threadIdx.x;
    const int tx = tid & 15;
    const int ty = tid >> 4;
    const int bm = blockIdx.x * 128;
    const int bn = blockIdx.y * 128;
    const int lrow = tid >> 1;
    const int lk = (tid & 1) * 8;

    float acc[8][8] = {};

    for (int k0 = 0; k0 < K; k0 += 16) {
        const float* ap = A + (size_t)(bm + lrow) * K + k0 + lk;
        const float* wp = W + (size_t)(bn + lrow) * K + k0 + lk;
        const float4 a0 = *(const float4*)ap;
        const float4 a1 = *(const float4*)(ap + 4);
        const float4 w0 = *(const float4*)wp;
        const float4 w1 = *(const float4*)(wp + 4);
        __syncthreads();
        As[lk+0][lrow] = a0.x; As[lk+1][lrow] = a0.y; As[lk+2][lrow] = a0.z; As[lk+3][lrow] = a0.w;
        As[lk+4][lrow] = a1.x; As[lk+5][lrow] = a1.y; As[lk+6][lrow] = a1.z; As[lk+7][lrow] = a1.w;
        Bs[lk+0][lrow] = w0.x; Bs[lk+1][lrow] = w0.y; Bs[lk+2][lrow] = w0.z; Bs[lk+3][lrow] = w0.w;
        Bs[lk+4][lrow] = w1.x; Bs[lk+5][lrow] = w1.y; Bs[lk+6][lrow] = w1.z; Bs[lk+7][lrow] = w1.w;
        __syncthreads();
#pragma unroll
        for (int k = 0; k < 16; k++) {
            const float4 av0 = *(const float4*)(&As[k][ty * 4]);
            const float4 av1 = *(const float4*)(&As[k][64 + ty * 4]);
            const float4 bv0 = *(const float4*)(&Bs[k][tx * 4]);
            const float4 bv1 = *(const float4*)(&Bs[k][64 + tx * 4]);
            const float ar[8] = {av0.x, av0.y, av0.z, av0.w, av1.x, av1.y, av1.z, av1.w};
            const float br[8] = {bv0.x, bv0.y, bv0.z, bv0.w, bv1.x, bv1.y, bv1.z, bv1.w};
#pragma unroll
            for (int i = 0; i < 8; i++)
#pragma unroll
                for (int j = 0; j < 8; j++) acc[i][j] += ar[i] * br[j];
        }
    }

    const int c0 = bn + tx * 4, c1 = bn + 64 + tx * 4;
    float4 bb0 = *(const float4*)(bias1 + c0);
    float4 bb1 = *(const float4*)(bias1 + c1);
    if (bias2) {
        const float4 e0 = *(const float4*)(bias2 + c0);
        const float4 e1 = *(const float4*)(bias2 + c1);
        bb0.x += e0.x; bb0.y += e0.y; bb0.z += e0.z; bb0.w += e0.w;
        bb1.x += e1.x; bb1.y += e1.y; bb1.z += e1.z; bb1.w += e1.w;
    }
#pragma unroll
    for (int ih = 0; ih < 2; ih++)
#pragma unroll
        for (int i = 0; i < 4; i++) {
            const int row = bm + ih * 64 + ty * 4 + i;
            const int ai = ih * 4 + i;
            float4 o0, o1;
            o0.x = acc[ai][0] + bb0.x; o0.y = acc[ai][1] + bb0.y;
            o0.z = acc[ai][2] + bb0.z; o0.w = acc[ai][3] + bb0.w;
            o1.x = acc[ai][4] + bb1.x; o1.y = acc[ai][5] + bb1.y;
            o1.z = acc[ai][6] + bb1.z; o1.w = acc[ai][7] + bb1.w;
            *(float4*)(C + (size_t)row * N + c0) = o0;
            *(float4*)(C + (size_t)row * N + c1) = o1;
        }
}

// ---------------------------------------------------------------------------
// Q projection at the last position only.
// ---------------------------------------------------------------------------
__global__ __launch_bounds__(256) void qlast_kernel(
    const float* __restrict__ h1, const float* __restrict__ wq,
    const float* __restrict__ bq, float* __restrict__ qout)
{
    const int b = blockIdx.x;
    const int t = threadIdx.x;
    __shared__ __align__(16) float hs[HID];
    hs[t] = h1[((size_t)b * SEQ + (SEQ - 1)) * HID + t];
    __syncthreads();
    const float4* wr = (const float4*)(wq + (size_t)t * HID);
    float acc = 0.0f;
#pragma unroll
    for (int k = 0; k < 64; k++) {
        const float4 wv = wr[k];
        const float4 hv = ((const float4*)hs)[k];
        acc += wv.x*hv.x + wv.y*hv.y + wv.z*hv.z + wv.w*hv.w;
    }
    qout[b * HID + t] = acc + bq[t];
}

// ---------------------------------------------------------------------------
// Decode attention at query S-1 with multiplicative decay on scores.
// ---------------------------------------------------------------------------
__global__ __launch_bounds__(256) void attn_kernel(
    const float* __restrict__ Kb, const float* __restrict__ Vb,
    const float* __restrict__ q, float* __restrict__ attn)
{
    const int b = blockIdx.x >> 2;
    const int h = blockIdx.x & 3;
    const int tid = threadIdx.x;

    __shared__ __align__(16) float qs[64];
    __shared__ float sc[SEQ];
    __shared__ float red[256];
    __shared__ float part[4][64];

    if (tid < 64) qs[tid] = q[b * HID + h * 64 + tid];
    __syncthreads();

    const float LN095 = -0.051293294387550533f;  // ln(0.95)
    for (int k = tid; k < SEQ; k += 256) {
        const float4* kr = (const float4*)(Kb + ((size_t)b * SEQ + k) * HID + h * 64);
        float acc = 0.0f;
#pragma unroll
        for (int d = 0; d < 16; d++) {
            const float4 kv = kr[d];
            const float4 qv = ((const float4*)qs)[d];
            acc += kv.x*qv.x + kv.y*qv.y + kv.z*qv.z + kv.w*qv.w;
        }
        const float dec = __expf(LN095 * (float)(SEQ - 1 - k));
        sc[k] = acc * 0.125f * dec;
    }
    __syncthreads();

    float m = -INFINITY;
    for (int k = tid; k < SEQ; k += 256) m = fmaxf(m, sc[k]);
    red[tid] = m;
    for (int off = 128; off > 0; off >>= 1) {
        __syncthreads();
        if (tid < off) red[tid] = fmaxf(red[tid], red[tid + off]);
    }
    __syncthreads();
    const float mx = red[0];

    float local = 0.0f;
    for (int k = tid; k < SEQ; k += 256) {
        const float p = expf(sc[k] - mx);
        sc[k] = p;
        local += p;
    }
    __syncthreads();
    red[tid] = local;
    for (int off = 128; off > 0; off >>= 1) {
        __syncthreads();
        if (tid < off) red[tid] += red[tid + off];
    }
    __syncthreads();
    const float total = red[0];

    const int chunk = tid >> 6;
    const int d = tid & 63;
    float acc = 0.0f;
    const int k0 = chunk * (SEQ / 4), k1 = (chunk + 1) * (SEQ / 4);
    for (int k = k0; k < k1; k++)
        acc += sc[k] * Vb[((size_t)b * SEQ + k) * HID + h * 64 + d];
    part[chunk][d] = acc;
    __syncthreads();
    if (tid < 64) {
        const float r = (part[0][tid] + part[1][tid]) + (part[2][tid] + part[3][tid]);
        attn[b * HID + h * 64 + tid] = r / total;
    }
}

// ---------------------------------------------------------------------------
// Head: context = attn @ wo^T + bo ; mean/log_var heads (5 each).
// ---------------------------------------------------------------------------
__global__ __launch_bounds__(256) void head_kernel(
    const float* __restrict__ attn, const float* __restrict__ wo,
    const float* __restrict__ bo, const float* __restrict__ w_mean,
    const float* __restrict__ b_mean, const float* __restrict__ w_var,
    const float* __restrict__ b_var, float* __restrict__ out)
{
    const int b = blockIdx.x;
    const int t = threadIdx.x;
    __shared__ __align__(16) float av[HID];
    __shared__ __align__(16) float ctx[HID];
    av[t] = attn[b * HID + t];
    __syncthreads();
    {
        const float4* wr = (const float4*)(wo + (size_t)t * HID);
        float acc = 0.0f;
#pragma unroll
        for (int k = 0; k < 64; k++) {
            const float4 wv = wr[k];
            const float4 hv = ((const float4*)av)[k];
            acc += wv.x*hv.x + wv.y*hv.y + wv.z*hv.z + wv.w*hv.w;
        }
        ctx[t] = acc + bo[t];
    }
    __syncthreads();
    if (t < 5) {
        const float4* wr = (const float4*)(w_mean + (size_t)t * HID);
        float acc = 0.0f;
#pragma unroll
        for (int k = 0; k < 64; k++) {
            const float4 wv = wr[k];
            const float4 hv = ((const float4*)ctx)[k];
            acc += wv.x*hv.x + wv.y*hv.y + wv.z*hv.z + wv.w*hv.w;
        }
        out[b * 5 + t] = acc + b_mean[t];
    } else if (t >= 8 && t < 13) {
        const int m = t - 8;
        const float4* wr = (const float4*)(w_var + (size_t)m * HID);
        float acc = 0.0f;
#pragma unroll
        for (int k = 0; k < 64; k++) {
            const float4 wv = wr[k];
            const float4 hv = ((const float4*)ctx)[k];
            acc += wv.x*hv.x + wv.y*hv.y + wv.z*hv.z + wv.w*hv.w;
        }
        out[BATCH * 5 + b * 5 + m] = acc + b_var[m];
    }
}

// ---------------------------------------------------------------------------
extern "C" void kernel_launch(void* const* d_in, const int* in_sizes, int n_in,
                              void* d_out, int out_size, void* d_ws, size_t ws_size,
                              hipStream_t stream) {
    const float* x      = (const float*)d_in[0];
    const float* w_ih0  = (const float*)d_in[1];
    const float* w_hh0  = (const float*)d_in[2];
    const float* b_ih0  = (const float*)d_in[3];
    const float* b_hh0  = (const float*)d_in[4];
    const float* w_ih1  = (const float*)d_in[5];
    const float* w_hh1  = (const float*)d_in[6];
    const float* b_ih1  = (const float*)d_in[7];
    const float* b_hh1  = (const float*)d_in[8];
    const float* wq     = (const float*)d_in[9];
    const float* bq     = (const float*)d_in[10];
    const float* wk     = (const float*)d_in[11];
    const float* bk     = (const float*)d_in[12];
    const float* wv     = (const float*)d_in[13];
    const float* bv     = (const float*)d_in[14];
    const float* wo     = (const float*)d_in[15];
    const float* bo     = (const float*)d_in[16];
    const float* w_mean = (const float*)d_in[17];
    const float* b_mean = (const float*)d_in[18];
    const float* w_var  = (const float*)d_in[19];
    const float* b_var  = (const float*)d_in[20];
    float* out = (float*)d_out;

    // ws layout (80 MB total, same as R1):
    //  [0, 64MB): xp region. lstm0 uses rows (b,2047) as slot scratch; then
    //             xproj1 GEMM fills it; lstm1 reads it (+ slot overlays);
    //             then reused as Kbuf|Vbuf|qbuf|abuf.
    //  [64MB, 80MB): hbuf (h0, then h1 in place).
    float* wsf  = (float*)d_ws;
    float* xp   = wsf;
    float* hbuf = wsf + (size_t)16384 * 1024;
    float* Kbuf = xp;
    float* Vbuf = xp + (size_t)16384 * 256;
    float* qbuf = xp + (size_t)2 * 16384 * 256;
    float* abuf = qbuf + BATCH * HID;

    // 1. LSTM layer 0 (input proj fused), h0 -> hbuf
    lstm_mb<0><<<32, 512, 0, stream>>>(x, w_hh0, w_ih0, b_ih0, b_hh0, xp, hbuf);
    // 2. xproj1 = h0 @ w_ih1^T + b_ih1 + b_hh1
    gemm_nt_bias<<<dim3(128, 8), 256, 0, stream>>>(hbuf, w_ih1, b_ih1, b_hh1, xp, 16384, 1024, 256);
    // 3. LSTM layer 1, h1 -> hbuf (in place over h0)
    lstm_mb<1><<<32, 512, 0, stream>>>(xp, w_hh1, nullptr, nullptr, nullptr, xp, hbuf);
    // 4. K, V projections
    gemm_nt_bias<<<dim3(128, 2), 256, 0, stream>>>(hbuf, wk, bk, nullptr, Kbuf, 16384, 256, 256);
    gemm_nt_bias<<<dim3(128, 2), 256, 0, stream>>>(hbuf, wv, bv, nullptr, Vbuf, 16384, 256, 256);
    // 5. Q at last position
    qlast_kernel<<<BATCH, 256, 0, stream>>>(hbuf, wq, bq, qbuf);
    // 6. decode attention with decay
    attn_kernel<<<BATCH * 4, 256, 0, stream>>>(Kbuf, Vbuf, qbuf, abuf);
    // 7. output proj + gaussian head
    head_kernel<<<BATCH, 256, 0, stream>>>(abuf, wo, bo, w_mean, b_mean, w_var, b_var, out);
}

// Round 3
// 7664.217 us; speedup vs baseline: 9.7485x; 2.7167x over previous
//
#include <hip/hip_runtime.h>
#include <math.h>

#define BATCH 8
#define SEQ   2048
#define IN    8
#define HID   256
#define G4    1024   // 4*HID

typedef unsigned long long u64;
typedef unsigned int u32;

__device__ __forceinline__ float sigmoidf_(float x) { return 1.0f / (1.0f + __expf(-x)); }
__device__ __forceinline__ float tanhf_(float x) { return 1.0f - 2.0f / (__expf(2.0f * x) + 1.0f); }
// padded LDS index for h: +4 words per 32 -> 8 distinct bank groups, conflict-free
__device__ __forceinline__ int hpad(int k) { return k + 4 * (k >> 5); }

// ---------------------------------------------------------------------------
// Multi-block LSTM recurrence. 4 blocks per batch (grid=32: b=idx&7, q=idx>>3).
// Thread (rg=t>>3, ks=t&7) holds 4 gate rows x 32-K weight slice in 128 VGPRs.
// Cross-block h exchange: tagged u64 slots {tag<<32 | h_bits}. The payload is
// INSIDE the atomic word, so RELAXED atomics suffice (R2's acquire/release
// emitted per-poll L2 invalidates + per-publish vmcnt drains -> 62 GB fetch).
// Only two fences: RELEASE on the first publish (orders the MODE1 xpl preload
// before any peer can overwrite xp row 2047), ACQUIRE once after the loop
// (orders the exit stores after the final polls).
// Slot overlays (dead ws rows):  even tags -> xp row (b,2047) floats [0,512)
//                                odd  tags -> h_out rows (b,2046..2047)
// Overwrite-safety chain (unchanged from R2): a parity slot is rewritten
// (tag+2) only after every peer consumed tag, via each block's syncthreads
// after its poll loop. Double-buffered h_lds -> single syncthreads per step.
// MODE 0: layer0, input proj (K=8) fused. MODE 1: layer1, reads xp[B][S][1024].
// ---------------------------------------------------------------------------
template<int MODE>
__global__ __launch_bounds__(512, 2) void lstm_mb(
    const float* __restrict__ xin,    // MODE0: x [B][S][8]; MODE1: xp [B][S][1024]
    const float* __restrict__ w_hh,   // [1024][256]
    const float* __restrict__ w_ih,   // MODE0: [1024][8]
    const float* __restrict__ b_ih,   // MODE0
    const float* __restrict__ b_hh,   // MODE0
    float* __restrict__ scratch,      // xproj region base (even-slot host)
    float* __restrict__ h_out)        // [B][S][256]
{
    const int b  = blockIdx.x & 7;
    const int q  = blockIdx.x >> 3;
    const int t  = threadIdx.x;
    const int ks = t & 7;          // K-slice 0..7 (32 floats each)
    const int rg = t >> 3;         // unit-local 0..63
    const int wv = t >> 6;         // wave 0..7
    const int lane = t & 63;
    const bool isg = (ks == 0);    // gate/nonlinearity lanes

    // ---- per-thread weights: rows G_j = 256j + 64q + rg, cols [32ks,32ks+32)
    float4 w4[4][8];
#pragma unroll
    for (int j = 0; j < 4; j++) {
        const float4* wr = (const float4*)(w_hh + ((size_t)(256 * j + 64 * q + rg)) * HID + ks * 32);
#pragma unroll
        for (int i = 0; i < 8; i++) w4[j][i] = wr[i];
    }

    // MODE0: input-proj weights + bias; MODE1: preload j0/j1 of xp row 2047
    float4 wi[4][2];
    float bs[4];
    float xpl0 = 0.0f, xpl1 = 0.0f;
    if constexpr (MODE == 0) {
#pragma unroll
        for (int j = 0; j < 4; j++) {
            const int G = 256 * j + 64 * q + rg;
            wi[j][0] = *(const float4*)(w_ih + (size_t)G * IN);
            wi[j][1] = *(const float4*)(w_ih + (size_t)G * IN + 4);
            bs[j] = b_ih[G] + b_hh[G];
        }
    } else {
        const float* xl = xin + ((size_t)b * SEQ + (SEQ - 1)) * G4;
        xpl0 = xl[64 * q + rg];
        xpl1 = xl[256 + 64 * q + rg];
    }

    // slot areas
    u64* se = (u64*)(scratch + ((size_t)b * SEQ + (SEQ - 1)) * G4);   // even tags
    u64* so = (u64*)(h_out + ((size_t)b * SEQ + (SEQ - 2)) * HID);    // odd tags

    __shared__ float h_lds[2][288];   // double buffer: read s&1, write (s+1)&1
    for (int i = t; i < 288; i += 512) { h_lds[0][i] = 0.0f; h_lds[1][i] = 0.0f; }
    __syncthreads();

    float c = 0.0f, h46 = 0.0f, h47 = 0.0f;
    const float* xb = (MODE == 0) ? (xin + (size_t)b * SEQ * IN) : (xin + (size_t)b * SEQ * G4);
    float* ho = h_out + (size_t)b * SEQ * HID;

    // ---- preload input contribution for s=0 (gate lanes)
    float xv0 = 0.0f, xv1 = 0.0f, xv2 = 0.0f, xv3 = 0.0f;
    if (isg) {
        if constexpr (MODE == 0) {
            const float4 xa = *(const float4*)(xb);
            const float4 xc = *(const float4*)(xb + 4);
#pragma unroll
            for (int j = 0; j < 4; j++) {
                float v = bs[j] + wi[j][0].x*xa.x + wi[j][0].y*xa.y + wi[j][0].z*xa.z + wi[j][0].w*xa.w
                                + wi[j][1].x*xc.x + wi[j][1].y*xc.y + wi[j][1].z*xc.z + wi[j][1].w*xc.w;
                if (j == 0) xv0 = v; else if (j == 1) xv1 = v; else if (j == 2) xv2 = v; else xv3 = v;
            }
        } else {
            const float* xr = xb + 64 * q + rg;
            xv0 = xr[0]; xv1 = xr[256]; xv2 = xr[512]; xv3 = xr[768];
        }
    }

    for (int s = 0; s < SEQ; s++) {
        const int cur = s & 1, nxt = cur ^ 1;

        // ---- prefetch next step's input early (latency hidden behind matvec+exchange)
        float xn0 = 0.0f, xn1 = 0.0f, xn2 = 0.0f, xn3 = 0.0f;
        if (isg && s + 1 < SEQ) {
            if constexpr (MODE == 0) {
                const float4 xa = *(const float4*)(xb + (size_t)(s + 1) * IN);
                const float4 xc = *(const float4*)(xb + (size_t)(s + 1) * IN + 4);
                xn0 = bs[0] + wi[0][0].x*xa.x + wi[0][0].y*xa.y + wi[0][0].z*xa.z + wi[0][0].w*xa.w
                            + wi[0][1].x*xc.x + wi[0][1].y*xc.y + wi[0][1].z*xc.z + wi[0][1].w*xc.w;
                xn1 = bs[1] + wi[1][0].x*xa.x + wi[1][0].y*xa.y + wi[1][0].z*xa.z + wi[1][0].w*xa.w
                            + wi[1][1].x*xc.x + wi[1][1].y*xc.y + wi[1][1].z*xc.z + wi[1][1].w*xc.w;
                xn2 = bs[2] + wi[2][0].x*xa.x + wi[2][0].y*xa.y + wi[2][0].z*xa.z + wi[2][0].w*xa.w
                            + wi[2][1].x*xc.x + wi[2][1].y*xc.y + wi[2][1].z*xc.z + wi[2][1].w*xc.w;
                xn3 = bs[3] + wi[3][0].x*xa.x + wi[3][0].y*xa.y + wi[3][0].z*xa.z + wi[3][0].w*xa.w
                            + wi[3][1].x*xc.x + wi[3][1].y*xc.y + wi[3][1].z*xc.z + wi[3][1].w*xc.w;
            } else {
                const float* xr = xb + (size_t)(s + 1) * G4 + 64 * q + rg;
                if (s + 1 == SEQ - 1) { xn0 = xpl0; xn1 = xpl1; }  // cols [0,512) overlaid by even slots
                else                  { xn0 = xr[0]; xn1 = xr[256]; }
                xn2 = xr[512]; xn3 = xr[768];                      // [512,1024) never clobbered
            }
        }

        // ---- matvec partials over own K-slice (conflict-free broadcast reads)
        float a0 = 0.0f, a1 = 0.0f, a2 = 0.0f, a3 = 0.0f;
#pragma unroll
        for (int i = 0; i < 8; i++) {
            const float4 h4 = *(const float4*)(&h_lds[cur][36 * ks + 4 * i]);
            a0 += w4[0][i].x*h4.x + w4[0][i].y*h4.y + w4[0][i].z*h4.z + w4[0][i].w*h4.w;
            a1 += w4[1][i].x*h4.x + w4[1][i].y*h4.y + w4[1][i].z*h4.z + w4[1][i].w*h4.w;
            a2 += w4[2][i].x*h4.x + w4[2][i].y*h4.y + w4[2][i].z*h4.z + w4[2][i].w*h4.w;
            a3 += w4[3][i].x*h4.x + w4[3][i].y*h4.y + w4[3][i].z*h4.z + w4[3][i].w*h4.w;
        }

        // ---- butterfly reduce across the 8 K-slices (lane bits 0..2)
#pragma unroll
        for (int m = 1; m <= 4; m <<= 1) {
            a0 += __shfl_xor(a0, m);
            a1 += __shfl_xor(a1, m);
            a2 += __shfl_xor(a2, m);
            a3 += __shfl_xor(a3, m);
        }

        const u32 tag = (u32)(s + 1);
        u64* sl = (tag & 1u) ? so : se;

        if (isg) {
            const float iv = sigmoidf_(a0 + xv0);
            const float fv = sigmoidf_(a1 + xv1);
            const float gv = tanhf_(a2 + xv2);
            const float ov = sigmoidf_(a3 + xv3);
            c = fv * c + iv * gv;
            const float hv = ov * tanhf_(c);
            const int u = 64 * q + rg;
            h_lds[nxt][hpad(u)] = hv;
            if (s == SEQ - 2)      h46 = hv;     // rows 2046/2047 are odd-slot area:
            else if (s == SEQ - 1) h47 = hv;     // stored after exit handshake
            else                   ho[(size_t)s * HID + u] = hv;
            const u64 pk = ((u64)tag << 32) | (u64)__float_as_uint(hv);
            if (s == 0)
                __hip_atomic_store(&sl[u], pk, __ATOMIC_RELEASE, __HIP_MEMORY_SCOPE_AGENT);
            else
                __hip_atomic_store(&sl[u], pk, __ATOMIC_RELAXED, __HIP_MEMORY_SCOPE_AGENT);
            xv0 = xn0; xv1 = xn1; xv2 = xn2; xv3 = xn3;
        }
        // waves 1..3: fetch the 3 foreign 64-unit chunks (publish-before-poll)
        if (wv >= 1 && wv <= 3) {
            const int f = (q + wv) & 3;
            const int u = 64 * f + lane;
            u64* sp = &sl[u];
            u64 v;
            do {
                v = __hip_atomic_load(sp, __ATOMIC_RELAXED, __HIP_MEMORY_SCOPE_AGENT);
            } while ((u32)(v >> 32) != tag);
            h_lds[nxt][hpad(u)] = __uint_as_float((u32)v);
        }
        __syncthreads();   // h_{s+1} fully assembled; also the slot-reuse ordering point
    }

    // exit: the tag-2048 round implies every peer finished its odd polls =>
    // safe to overwrite the odd-slot rows with the real final h values.
    __builtin_amdgcn_fence(__ATOMIC_ACQUIRE, "agent");
    if (isg) {
        const int u = 64 * q + rg;
        ho[(size_t)(SEQ - 2) * HID + u] = h46;
        ho[(size_t)(SEQ - 1) * HID + u] = h47;
    }
}

// ---------------------------------------------------------------------------
// NT GEMM: C[M][N] = A[M][K] @ W[N][K]^T + bias1 (+bias2). 128x128x16 tiles,
// 256 threads, 8x8 micro-tile.
// ---------------------------------------------------------------------------
__global__ __launch_bounds__(256) void gemm_nt_bias(
    const float* __restrict__ A, const float* __restrict__ W,
    const float* __restrict__ bias1, const float* __restrict__ bias2,
    float* __restrict__ C, int M, int N, int K)
{
    __shared__ float As[16][132];
    __shared__ float Bs[16][132];
    const int tid = threadIdx.x;
    const int tx = tid & 15;
    const int ty = tid >> 4;
    const int bm = blockIdx.x * 128;
    const int bn = blockIdx.y * 128;
    const int lrow = tid >> 1;
    const int lk = (tid & 1) * 8;

    float acc[8][8] = {};

    for (int k0 = 0; k0 < K; k0 += 16) {
        const float* ap = A + (size_t)(bm + lrow) * K + k0 + lk;
        const float* wp = W + (size_t)(bn + lrow) * K + k0 + lk;
        const float4 a0 = *(const float4*)ap;
        const float4 a1 = *(const float4*)(ap + 4);
        const float4 w0 = *(const float4*)wp;
        const float4 w1 = *(const float4*)(wp + 4);
        __syncthreads();
        As[lk+0][lrow] = a0.x; As[lk+1][lrow] = a0.y; As[lk+2][lrow] = a0.z; As[lk+3][lrow] = a0.w;
        As[lk+4][lrow] = a1.x; As[lk+5][lrow] = a1.y; As[lk+6][lrow] = a1.z; As[lk+7][lrow] = a1.w;
        Bs[lk+0][lrow] = w0.x; Bs[lk+1][lrow] = w0.y; Bs[lk+2][lrow] = w0.z; Bs[lk+3][lrow] = w0.w;
        Bs[lk+4][lrow] = w1.x; Bs[lk+5][lrow] = w1.y; Bs[lk+6][lrow] = w1.z; Bs[lk+7][lrow] = w1.w;
        __syncthreads();
#pragma unroll
        for (int k = 0; k < 16; k++) {
            const float4 av0 = *(const float4*)(&As[k][ty * 4]);
            const float4 av1 = *(const float4*)(&As[k][64 + ty * 4]);
            const float4 bv0 = *(const float4*)(&Bs[k][tx * 4]);
            const float4 bv1 = *(const float4*)(&Bs[k][64 + tx * 4]);
            const float ar[8] = {av0.x, av0.y, av0.z, av0.w, av1.x, av1.y, av1.z, av1.w};
            const float br[8] = {bv0.x, bv0.y, bv0.z, bv0.w, bv1.x, bv1.y, bv1.z, bv1.w};
#pragma unroll
            for (int i = 0; i < 8; i++)
#pragma unroll
                for (int j = 0; j < 8; j++) acc[i][j] += ar[i] * br[j];
        }
    }

    const int c0 = bn + tx * 4, c1 = bn + 64 + tx * 4;
    float4 bb0 = *(const float4*)(bias1 + c0);
    float4 bb1 = *(const float4*)(bias1 + c1);
    if (bias2) {
        const float4 e0 = *(const float4*)(bias2 + c0);
        const float4 e1 = *(const float4*)(bias2 + c1);
        bb0.x += e0.x; bb0.y += e0.y; bb0.z += e0.z; bb0.w += e0.w;
        bb1.x += e1.x; bb1.y += e1.y; bb1.z += e1.z; bb1.w += e1.w;
    }
#pragma unroll
    for (int ih = 0; ih < 2; ih++)
#pragma unroll
        for (int i = 0; i < 4; i++) {
            const int row = bm + ih * 64 + ty * 4 + i;
            const int ai = ih * 4 + i;
            float4 o0, o1;
            o0.x = acc[ai][0] + bb0.x; o0.y = acc[ai][1] + bb0.y;
            o0.z = acc[ai][2] + bb0.z; o0.w = acc[ai][3] + bb0.w;
            o1.x = acc[ai][4] + bb1.x; o1.y = acc[ai][5] + bb1.y;
            o1.z = acc[ai][6] + bb1.z; o1.w = acc[ai][7] + bb1.w;
            *(float4*)(C + (size_t)row * N + c0) = o0;
            *(float4*)(C + (size_t)row * N + c1) = o1;
        }
}

// ---------------------------------------------------------------------------
// Q projection at the last position only.
// ---------------------------------------------------------------------------
__global__ __launch_bounds__(256) void qlast_kernel(
    const float* __restrict__ h1, const float* __restrict__ wq,
    const float* __restrict__ bq, float* __restrict__ qout)
{
    const int b = blockIdx.x;
    const int t = threadIdx.x;
    __shared__ __align__(16) float hs[HID];
    hs[t] = h1[((size_t)b * SEQ + (SEQ - 1)) * HID + t];
    __syncthreads();
    const float4* wr = (const float4*)(wq + (size_t)t * HID);
    float acc = 0.0f;
#pragma unroll
    for (int k = 0; k < 64; k++) {
        const float4 wv = wr[k];
        const float4 hv = ((const float4*)hs)[k];
        acc += wv.x*hv.x + wv.y*hv.y + wv.z*hv.z + wv.w*hv.w;
    }
    qout[b * HID + t] = acc + bq[t];
}

// ---------------------------------------------------------------------------
// Decode attention at query S-1 with multiplicative decay on scores.
// ---------------------------------------------------------------------------
__global__ __launch_bounds__(256) void attn_kernel(
    const float* __restrict__ Kb, const float* __restrict__ Vb,
    const float* __restrict__ q, float* __restrict__ attn)
{
    const int b = blockIdx.x >> 2;
    const int h = blockIdx.x & 3;
    const int tid = threadIdx.x;

    __shared__ __align__(16) float qs[64];
    __shared__ float sc[SEQ];
    __shared__ float red[256];
    __shared__ float part[4][64];

    if (tid < 64) qs[tid] = q[b * HID + h * 64 + tid];
    __syncthreads();

    const float LN095 = -0.051293294387550533f;  // ln(0.95)
    for (int k = tid; k < SEQ; k += 256) {
        const float4* kr = (const float4*)(Kb + ((size_t)b * SEQ + k) * HID + h * 64);
        float acc = 0.0f;
#pragma unroll
        for (int d = 0; d < 16; d++) {
            const float4 kv = kr[d];
            const float4 qv = ((const float4*)qs)[d];
            acc += kv.x*qv.x + kv.y*qv.y + kv.z*qv.z + kv.w*qv.w;
        }
        const float dec = __expf(LN095 * (float)(SEQ - 1 - k));
        sc[k] = acc * 0.125f * dec;
    }
    __syncthreads();

    float m = -INFINITY;
    for (int k = tid; k < SEQ; k += 256) m = fmaxf(m, sc[k]);
    red[tid] = m;
    for (int off = 128; off > 0; off >>= 1) {
        __syncthreads();
        if (tid < off) red[tid] = fmaxf(red[tid], red[tid + off]);
    }
    __syncthreads();
    const float mx = red[0];

    float local = 0.0f;
    for (int k = tid; k < SEQ; k += 256) {
        const float p = expf(sc[k] - mx);
        sc[k] = p;
        local += p;
    }
    __syncthreads();
    red[tid] = local;
    for (int off = 128; off > 0; off >>= 1) {
        __syncthreads();
        if (tid < off) red[tid] += red[tid + off];
    }
    __syncthreads();
    const float total = red[0];

    const int chunk = tid >> 6;
    const int d = tid & 63;
    float acc = 0.0f;
    const int k0 = chunk * (SEQ / 4), k1 = (chunk + 1) * (SEQ / 4);
    for (int k = k0; k < k1; k++)
        acc += sc[k] * Vb[((size_t)b * SEQ + k) * HID + h * 64 + d];
    part[chunk][d] = acc;
    __syncthreads();
    if (tid < 64) {
        const float r = (part[0][tid] + part[1][tid]) + (part[2][tid] + part[3][tid]);
        attn[b * HID + h * 64 + tid] = r / total;
    }
}

// ---------------------------------------------------------------------------
// Head: context = attn @ wo^T + bo ; mean/log_var heads (5 each).
// ---------------------------------------------------------------------------
__global__ __launch_bounds__(256) void head_kernel(
    const float* __restrict__ attn, const float* __restrict__ wo,
    const float* __restrict__ bo, const float* __restrict__ w_mean,
    const float* __restrict__ b_mean, const float* __restrict__ w_var,
    const float* __restrict__ b_var, float* __restrict__ out)
{
    const int b = blockIdx.x;
    const int t = threadIdx.x;
    __shared__ __align__(16) float av[HID];
    __shared__ __align__(16) float ctx[HID];
    av[t] = attn[b * HID + t];
    __syncthreads();
    {
        const float4* wr = (const float4*)(wo + (size_t)t * HID);
        float acc = 0.0f;
#pragma unroll
        for (int k = 0; k < 64; k++) {
            const float4 wv = wr[k];
            const float4 hv = ((const float4*)av)[k];
            acc += wv.x*hv.x + wv.y*hv.y + wv.z*hv.z + wv.w*hv.w;
        }
        ctx[t] = acc + bo[t];
    }
    __syncthreads();
    if (t < 5) {
        const float4* wr = (const float4*)(w_mean + (size_t)t * HID);
        float acc = 0.0f;
#pragma unroll
        for (int k = 0; k < 64; k++) {
            const float4 wv = wr[k];
            const float4 hv = ((const float4*)ctx)[k];
            acc += wv.x*hv.x + wv.y*hv.y + wv.z*hv.z + wv.w*hv.w;
        }
        out[b * 5 + t] = acc + b_mean[t];
    } else if (t >= 8 && t < 13) {
        const int m = t - 8;
        const float4* wr = (const float4*)(w_var + (size_t)m * HID);
        float acc = 0.0f;
#pragma unroll
        for (int k = 0; k < 64; k++) {
            const float4 wv = wr[k];
            const float4 hv = ((const float4*)ctx)[k];
            acc += wv.x*hv.x + wv.y*hv.y + wv.z*hv.z + wv.w*hv.w;
        }
        out[BATCH * 5 + b * 5 + m] = acc + b_var[m];
    }
}

// ---------------------------------------------------------------------------
extern "C" void kernel_launch(void* const* d_in, const int* in_sizes, int n_in,
                              void* d_out, int out_size, void* d_ws, size_t ws_size,
                              hipStream_t stream) {
    const float* x      = (const float*)d_in[0];
    const float* w_ih0  = (const float*)d_in[1];
    const float* w_hh0  = (const float*)d_in[2];
    const float* b_ih0  = (const float*)d_in[3];
    const float* b_hh0  = (const float*)d_in[4];
    const float* w_ih1  = (const float*)d_in[5];
    const float* w_hh1  = (const float*)d_in[6];
    const float* b_ih1  = (const float*)d_in[7];
    const float* b_hh1  = (const float*)d_in[8];
    const float* wq     = (const float*)d_in[9];
    const float* bq     = (const float*)d_in[10];
    const float* wk     = (const float*)d_in[11];
    const float* bk     = (const float*)d_in[12];
    const float* wv     = (const float*)d_in[13];
    const float* bv     = (const float*)d_in[14];
    const float* wo     = (const float*)d_in[15];
    const float* bo     = (const float*)d_in[16];
    const float* w_mean = (const float*)d_in[17];
    const float* b_mean = (const float*)d_in[18];
    const float* w_var  = (const float*)d_in[19];
    const float* b_var  = (const float*)d_in[20];
    float* out = (float*)d_out;

    // ws layout (80 MB):
    //  [0, 64MB): xp region. lstm0 even slots in rows (b,2047); xproj1 GEMM
    //             fills it; lstm1 reads (+ slot overlays); then K|V|q|attn.
    //  [64MB, 80MB): hbuf (h0, then h1 in place).
    float* wsf  = (float*)d_ws;
    float* xp   = wsf;
    float* hbuf = wsf + (size_t)16384 * 1024;
    float* Kbuf = xp;
    float* Vbuf = xp + (size_t)16384 * 256;
    float* qbuf = xp + (size_t)2 * 16384 * 256;
    float* abuf = qbuf + BATCH * HID;

    // 1. LSTM layer 0 (input proj fused), h0 -> hbuf
    lstm_mb<0><<<32, 512, 0, stream>>>(x, w_hh0, w_ih0, b_ih0, b_hh0, xp, hbuf);
    // 2. xproj1 = h0 @ w_ih1^T + b_ih1 + b_hh1
    gemm_nt_bias<<<dim3(128, 8), 256, 0, stream>>>(hbuf, w_ih1, b_ih1, b_hh1, xp, 16384, 1024, 256);
    // 3. LSTM layer 1, h1 -> hbuf (in place over h0)
    lstm_mb<1><<<32, 512, 0, stream>>>(xp, w_hh1, nullptr, nullptr, nullptr, xp, hbuf);
    // 4. K, V projections
    gemm_nt_bias<<<dim3(128, 2), 256, 0, stream>>>(hbuf, wk, bk, nullptr, Kbuf, 16384, 256, 256);
    gemm_nt_bias<<<dim3(128, 2), 256, 0, stream>>>(hbuf, wv, bv, nullptr, Vbuf, 16384, 256, 256);
    // 5. Q at last position
    qlast_kernel<<<BATCH, 256, 0, stream>>>(hbuf, wq, bq, qbuf);
    // 6. decode attention with decay
    attn_kernel<<<BATCH * 4, 256, 0, stream>>>(Kbuf, Vbuf, qbuf, abuf);
    // 7. output proj + gaussian head
    head_kernel<<<BATCH, 256, 0, stream>>>(abuf, wo, bo, w_mean, b_mean, w_var, b_var, out);
}

// Round 4
// 3613.979 us; speedup vs baseline: 20.6737x; 2.1207x over previous
//
#include <hip/hip_runtime.h>
#include <math.h>

#define BATCH 8
#define SEQ   2048
#define IN    8
#define HID   256
#define G4    1024   // 4*HID
#define XPR_R 64     // xp ring depth (steps)

typedef unsigned long long u64;
typedef unsigned int u32;

__device__ __forceinline__ float sigmoidf_(float x) { return 1.0f / (1.0f + __expf(-x)); }
__device__ __forceinline__ float tanhf_(float x) { return 1.0f - 2.0f / (__expf(2.0f * x) + 1.0f); }
// padded LDS index for h: +4 words per 32 -> 8 distinct bank groups, conflict-free
__device__ __forceinline__ int hpad(int k) { return k + 4 * (k >> 5); }

// Sum over the 8 lanes {base..base+7} (lane bits 0..2) using VALU DPP ops —
// keeps the reduce OFF the DS pipe (R3's shfl_xor emitted 128 ds_permute/step
// per CU on the same 128B/cy unit as the matvec ds_read_b128).
__device__ __forceinline__ float dpp_add8(float v) {
    int x;
    x = __builtin_amdgcn_update_dpp(0, __float_as_int(v), 0xB1, 0xF, 0xF, false);  // quad_perm [1,0,3,2] = xor1
    v += __int_as_float(x);
    x = __builtin_amdgcn_update_dpp(0, __float_as_int(v), 0x4E, 0xF, 0xF, false);  // quad_perm [2,3,0,1] = xor2
    v += __int_as_float(x);
    x = __builtin_amdgcn_update_dpp(0, __float_as_int(v), 0x141, 0xF, 0xF, false); // row_half_mirror (crosses quads)
    v += __int_as_float(x);
    return v;
}

// Tagged u64 word: {tag(s+1) << 32 | f32 bits}. Payload is inside the atomic
// word -> RELAXED suffices; cross-location ordering (ring reuse, back-pressure)
// rides on __syncthreads' vmcnt(0)-before-s_barrier drain.
__device__ __forceinline__ float poll_tag(const u64* p, u32 tag) {
    u64 v;
    do { v = __hip_atomic_load(p, __ATOMIC_RELAXED, __HIP_MEMORY_SCOPE_AGENT); }
    while ((u32)(v >> 32) != tag);
    return __uint_as_float((u32)v);
}
__device__ __forceinline__ void pub_tag(u64* p, u32 tag, float x) {
    __hip_atomic_store(p, ((u64)tag << 32) | (u64)__float_as_uint(x),
                       __ATOMIC_RELAXED, __HIP_MEMORY_SCOPE_AGENT);
}

__device__ __forceinline__ void matvec8(const float4 (&w4)[4][8], const float* hrow, int ks,
                                        float& a0, float& a1, float& a2, float& a3) {
    a0 = a1 = a2 = a3 = 0.0f;
#pragma unroll
    for (int i = 0; i < 8; i++) {
        const float4 h4 = *(const float4*)(&hrow[36 * ks + 4 * i]);  // 8-lane broadcast
        a0 += w4[0][i].x*h4.x + w4[0][i].y*h4.y + w4[0][i].z*h4.z + w4[0][i].w*h4.w;
        a1 += w4[1][i].x*h4.x + w4[1][i].y*h4.y + w4[1][i].z*h4.z + w4[1][i].w*h4.w;
        a2 += w4[2][i].x*h4.x + w4[2][i].y*h4.y + w4[2][i].z*h4.z + w4[2][i].w*h4.w;
        a3 += w4[3][i].x*h4.x + w4[3][i].y*h4.y + w4[3][i].z*h4.z + w4[3][i].w*h4.w;
    }
}

// ---------------------------------------------------------------------------
// Fused pipelined 2-layer LSTM. Grid = 96 blocks x 512 threads:
//   bid&7 = batch b (XCD-locality heuristic), bid>>3 = role 0..11:
//   role 0-3  : L0 recurrence block q  (owns h0 units [64q,64q+64))
//   role 4-7  : P  projection block p  (xp rows [256p,256p+256) of w_ih1)
//   role 8-11 : L1 recurrence block q
// Dataflow: L0 -> h0 write-once stream (peers + P consume; no flow control)
//           P  -> xp ring (64 steps) with back-pressure from L1's parity ring
//           L1 -> parity ring (3 lockstep peers, R3-proven invariant) + hbuf
// Thread (rg=t>>3, ks=t&7) holds 4 rows x 32-col weight slice in 128 VGPRs.
// ---------------------------------------------------------------------------
__global__ __launch_bounds__(512, 2) void lstm_fused(
    const float* __restrict__ x,
    const float* __restrict__ w_ih0, const float* __restrict__ w_hh0,
    const float* __restrict__ b_ih0, const float* __restrict__ b_hh0,
    const float* __restrict__ w_ih1, const float* __restrict__ w_hh1,
    const float* __restrict__ b_ih1, const float* __restrict__ b_hh1,
    u64* __restrict__ h0s,    // [8][2048][256] tagged, write-once
    u64* __restrict__ xpr,    // [8][64][1024]  tagged ring
    u64* __restrict__ h1r,    // [2][8][256]    tagged parity ring
    float* __restrict__ hbuf) // [8][2048][256] plain h1
{
    const int bid = blockIdx.x;
    const int b    = bid & 7;
    const int role = bid >> 3;
    const int grp  = role >> 2;   // 0 L0, 1 P, 2 L1
    const int q    = role & 3;
    const int t    = threadIdx.x;
    const int ks   = t & 7;
    const int rg   = t >> 3;
    const int wv   = t >> 6;
    const int lane = t & 63;
    const bool isg = (ks == 0);

    __shared__ float h_lds[2][288];
    __shared__ float xbuf[2][256];   // L1: xp values, layout [rg][gate j]

    u64* h0b = h0s + (size_t)b * SEQ * HID;
    u64* xpb = xpr + (size_t)b * XPR_R * G4;

    for (int i = t; i < 576; i += 512) ((float*)h_lds)[i] = 0.0f;
    __syncthreads();   // init must precede any pre-poll LDS write

    if (grp == 0) {
        // ================= L0: layer-0 recurrence, input proj fused =========
        float4 w4[4][8];
#pragma unroll
        for (int j = 0; j < 4; j++) {
            const float4* wr = (const float4*)(w_hh0 + (size_t)(256*j + 64*q + rg) * HID + ks * 32);
#pragma unroll
            for (int i = 0; i < 8; i++) w4[j][i] = wr[i];
        }
        float4 wi[4][2]; float bs4[4];
#pragma unroll
        for (int j = 0; j < 4; j++) {
            const int G = 256*j + 64*q + rg;
            wi[j][0] = *(const float4*)(w_ih0 + (size_t)G * IN);
            wi[j][1] = *(const float4*)(w_ih0 + (size_t)G * IN + 4);
            bs4[j] = b_ih0[G] + b_hh0[G];
        }
        const float* xb = x + (size_t)b * SEQ * IN;
        float c = 0.0f;
        float xv0 = 0, xv1 = 0, xv2 = 0, xv3 = 0;
        if (isg) {
            const float4 xa = *(const float4*)(xb);
            const float4 xc = *(const float4*)(xb + 4);
            xv0 = bs4[0] + wi[0][0].x*xa.x + wi[0][0].y*xa.y + wi[0][0].z*xa.z + wi[0][0].w*xa.w
                         + wi[0][1].x*xc.x + wi[0][1].y*xc.y + wi[0][1].z*xc.z + wi[0][1].w*xc.w;
            xv1 = bs4[1] + wi[1][0].x*xa.x + wi[1][0].y*xa.y + wi[1][0].z*xa.z + wi[1][0].w*xa.w
                         + wi[1][1].x*xc.x + wi[1][1].y*xc.y + wi[1][1].z*xc.z + wi[1][1].w*xc.w;
            xv2 = bs4[2] + wi[2][0].x*xa.x + wi[2][0].y*xa.y + wi[2][0].z*xa.z + wi[2][0].w*xa.w
                         + wi[2][1].x*xc.x + wi[2][1].y*xc.y + wi[2][1].z*xc.z + wi[2][1].w*xc.w;
            xv3 = bs4[3] + wi[3][0].x*xa.x + wi[3][0].y*xa.y + wi[3][0].z*xa.z + wi[3][0].w*xa.w
                         + wi[3][1].x*xc.x + wi[3][1].y*xc.y + wi[3][1].z*xc.z + wi[3][1].w*xc.w;
        }

        for (int s = 0; s < SEQ; s++) {
            const int cur = s & 1, nxt = cur ^ 1;
            float xn0 = 0, xn1 = 0, xn2 = 0, xn3 = 0;
            if (isg && s + 1 < SEQ) {
                const float4 xa = *(const float4*)(xb + (size_t)(s + 1) * IN);
                const float4 xc = *(const float4*)(xb + (size_t)(s + 1) * IN + 4);
                xn0 = bs4[0] + wi[0][0].x*xa.x + wi[0][0].y*xa.y + wi[0][0].z*xa.z + wi[0][0].w*xa.w
                             + wi[0][1].x*xc.x + wi[0][1].y*xc.y + wi[0][1].z*xc.z + wi[0][1].w*xc.w;
                xn1 = bs4[1] + wi[1][0].x*xa.x + wi[1][0].y*xa.y + wi[1][0].z*xa.z + wi[1][0].w*xa.w
                             + wi[1][1].x*xc.x + wi[1][1].y*xc.y + wi[1][1].z*xc.z + wi[1][1].w*xc.w;
                xn2 = bs4[2] + wi[2][0].x*xa.x + wi[2][0].y*xa.y + wi[2][0].z*xa.z + wi[2][0].w*xa.w
                             + wi[2][1].x*xc.x + wi[2][1].y*xc.y + wi[2][1].z*xc.z + wi[2][1].w*xc.w;
                xn3 = bs4[3] + wi[3][0].x*xa.x + wi[3][0].y*xa.y + wi[3][0].z*xa.z + wi[3][0].w*xa.w
                             + wi[3][1].x*xc.x + wi[3][1].y*xc.y + wi[3][1].z*xc.z + wi[3][1].w*xc.w;
            }
            float a0, a1, a2, a3;
            matvec8(w4, h_lds[cur], ks, a0, a1, a2, a3);
            a0 = dpp_add8(a0); a1 = dpp_add8(a1); a2 = dpp_add8(a2); a3 = dpp_add8(a3);
            const u32 tag = (u32)(s + 1);
            if (isg) {
                const float iv = sigmoidf_(a0 + xv0);
                const float fv = sigmoidf_(a1 + xv1);
                const float gv = tanhf_(a2 + xv2);
                const float ov = sigmoidf_(a3 + xv3);
                c = fv * c + iv * gv;
                const float hv = ov * tanhf_(c);
                const int u = 64*q + rg;
                h_lds[nxt][hpad(u)] = hv;
                pub_tag(&h0b[(size_t)s * HID + u], tag, hv);
                xv0 = xn0; xv1 = xn1; xv2 = xn2; xv3 = xn3;
            }
            if (wv >= 1 && wv <= 3) {
                const int u = 64 * ((q + wv) & 3) + lane;
                h_lds[nxt][hpad(u)] = poll_tag(&h0b[(size_t)s * HID + u], tag);
            }
            __syncthreads();
        }
    } else if (grp == 1) {
        // ================= P: xp[s] = w_ih1 @ h0[s] + biases ================
        const int p = q;
        float4 w4[4][8]; float bs4[4];
#pragma unroll
        for (int j = 0; j < 4; j++) {
            const int R = 256*p + 64*j + rg;
            const float4* wr = (const float4*)(w_ih1 + (size_t)R * HID + ks * 32);
#pragma unroll
            for (int i = 0; i < 8; i++) w4[j][i] = wr[i];
            bs4[j] = b_ih1[R] + b_hh1[R];
        }
        if (wv >= 4) {   // pre-poll h0[0]
            const int u = 64 * (wv - 4) + lane;
            h_lds[0][hpad(u)] = poll_tag(&h0b[u], 1u);
        }
        __syncthreads();

        for (int s = 0; s < SEQ; s++) {
            const int cur = s & 1, nxt = cur ^ 1;
            float a0, a1, a2, a3;
            matvec8(w4, h_lds[cur], ks, a0, a1, a2, a3);
            a0 = dpp_add8(a0); a1 = dpp_add8(a1); a2 = dpp_add8(a2); a3 = dpp_add8(a3);
            const u32 tag = (u32)(s + 1);
            if (isg) {
                // ring back-pressure: xp slot s%64 may hold xp[s-64], consumed by
                // L1 during its step s-65; safe once L1 passed step s-64, i.e. a
                // ring tag >= s-63 exists (poison 0xAAAAAAAA filtered by <=2048).
                if (s >= XPR_R) {
                    const u32 need = (u32)(s - (XPR_R - 1));
                    const u64* bp = h1r + ((size_t)(need & 1u) * 8 + b) * HID + (64*p + rg);
                    u32 tt;
                    do { tt = (u32)(__hip_atomic_load(bp, __ATOMIC_RELAXED, __HIP_MEMORY_SCOPE_AGENT) >> 32); }
                    while (!(tt >= need && tt <= 2048u));
                }
                u64* slot = xpb + (size_t)(s & (XPR_R - 1)) * G4 + 256*p + rg;
                pub_tag(slot +   0, tag, a0 + bs4[0]);
                pub_tag(slot +  64, tag, a1 + bs4[1]);
                pub_tag(slot + 128, tag, a2 + bs4[2]);
                pub_tag(slot + 192, tag, a3 + bs4[3]);
            }
            if (wv >= 4 && s + 1 < SEQ) {   // prefetch h0[s+1]
                const int u = 64 * (wv - 4) + lane;
                h_lds[nxt][hpad(u)] = poll_tag(&h0b[(size_t)(s + 1) * HID + u], tag + 1u);
            }
            __syncthreads();
        }
    } else {
        // ================= L1: layer-1 recurrence =========================
        float4 w4[4][8];
#pragma unroll
        for (int j = 0; j < 4; j++) {
            const float4* wr = (const float4*)(w_hh1 + (size_t)(256*j + 64*q + rg) * HID + ks * 32);
#pragma unroll
            for (int i = 0; i < 8; i++) w4[j][i] = wr[i];
        }
        float* ho = hbuf + (size_t)b * SEQ * HID;
        if (wv >= 4) {   // pre-poll xp[0]
            const int j = wv - 4;
            xbuf[0][4*lane + j] = poll_tag(&xpb[256*j + 64*q + lane], 1u);
        }
        __syncthreads();

        float c = 0.0f;
        for (int s = 0; s < SEQ; s++) {
            const int cur = s & 1, nxt = cur ^ 1;
            float a0, a1, a2, a3;
            matvec8(w4, h_lds[cur], ks, a0, a1, a2, a3);
            a0 = dpp_add8(a0); a1 = dpp_add8(a1); a2 = dpp_add8(a2); a3 = dpp_add8(a3);
            const u32 tag = (u32)(s + 1);
            if (isg) {
                const float4 xq = *(const float4*)(&xbuf[cur][4*rg]);
                const float iv = sigmoidf_(a0 + xq.x);
                const float fv = sigmoidf_(a1 + xq.y);
                const float gv = tanhf_(a2 + xq.z);
                const float ov = sigmoidf_(a3 + xq.w);
                c = fv * c + iv * gv;
                const float hv = ov * tanhf_(c);
                const int u = 64*q + rg;
                h_lds[nxt][hpad(u)] = hv;
                ho[(size_t)s * HID + u] = hv;
                pub_tag(&h1r[((size_t)(tag & 1u) * 8 + b) * HID + u], tag, hv);
            }
            if (wv >= 1 && wv <= 3) {   // peer exchange (parity ring, lockstep)
                const int u = 64 * ((q + wv) & 3) + lane;
                h_lds[nxt][hpad(u)] = poll_tag(&h1r[((size_t)(tag & 1u) * 8 + b) * HID + u], tag);
            }
            if (wv >= 4 && s + 1 < SEQ) {   // prefetch xp[s+1]
                const int j = wv - 4;
                xbuf[nxt][4*lane + j] =
                    poll_tag(&xpb[(size_t)((s + 1) & (XPR_R - 1)) * G4 + 256*j + 64*q + lane], tag + 1u);
            }
            __syncthreads();
        }
    }
}

// ---------------------------------------------------------------------------
// K and V projections in one launch (blockIdx.z selects). NT GEMM,
// 128x128x16 tiles, 256 threads, 8x8 micro-tile.
// ---------------------------------------------------------------------------
__global__ __launch_bounds__(256) void gemm_kv(
    const float* __restrict__ A,
    const float* __restrict__ Wk, const float* __restrict__ bk,
    const float* __restrict__ Wv, const float* __restrict__ bv,
    float* __restrict__ Ck, float* __restrict__ Cv, int M, int N, int K)
{
    const float* W    = blockIdx.z ? Wv : Wk;
    const float* bias = blockIdx.z ? bv : bk;
    float*       C    = blockIdx.z ? Cv : Ck;

    __shared__ float As[16][132];
    __shared__ float Bs[16][132];
    const int tid = threadIdx.x;
    const int tx = tid & 15;
    const int ty = tid >> 4;
    const int bm = blockIdx.x * 128;
    const int bn = blockIdx.y * 128;
    const int lrow = tid >> 1;
    const int lk = (tid & 1) * 8;

    float acc[8][8] = {};

    for (int k0 = 0; k0 < K; k0 += 16) {
        const float* ap = A + (size_t)(bm + lrow) * K + k0 + lk;
        const float* wp = W + (size_t)(bn + lrow) * K + k0 + lk;
        const float4 a0 = *(const float4*)ap;
        const float4 a1 = *(const float4*)(ap + 4);
        const float4 w0 = *(const float4*)wp;
        const float4 w1 = *(const float4*)(wp + 4);
        __syncthreads();
        As[lk+0][lrow] = a0.x; As[lk+1][lrow] = a0.y; As[lk+2][lrow] = a0.z; As[lk+3][lrow] = a0.w;
        As[lk+4][lrow] = a1.x; As[lk+5][lrow] = a1.y; As[lk+6][lrow] = a1.z; As[lk+7][lrow] = a1.w;
        Bs[lk+0][lrow] = w0.x; Bs[lk+1][lrow] = w0.y; Bs[lk+2][lrow] = w0.z; Bs[lk+3][lrow] = w0.w;
        Bs[lk+4][lrow] = w1.x; Bs[lk+5][lrow] = w1.y; Bs[lk+6][lrow] = w1.z; Bs[lk+7][lrow] = w1.w;
        __syncthreads();
#pragma unroll
        for (int k = 0; k < 16; k++) {
            const float4 av0 = *(const float4*)(&As[k][ty * 4]);
            const float4 av1 = *(const float4*)(&As[k][64 + ty * 4]);
            const float4 bv0 = *(const float4*)(&Bs[k][tx * 4]);
            const float4 bv1 = *(const float4*)(&Bs[k][64 + tx * 4]);
            const float ar[8] = {av0.x, av0.y, av0.z, av0.w, av1.x, av1.y, av1.z, av1.w};
            const float br[8] = {bv0.x, bv0.y, bv0.z, bv0.w, bv1.x, bv1.y, bv1.z, bv1.w};
#pragma unroll
            for (int i = 0; i < 8; i++)
#pragma unroll
                for (int j = 0; j < 8; j++) acc[i][j] += ar[i] * br[j];
        }
    }

    const int c0 = bn + tx * 4, c1 = bn + 64 + tx * 4;
    const float4 bb0 = *(const float4*)(bias + c0);
    const float4 bb1 = *(const float4*)(bias + c1);
#pragma unroll
    for (int ih = 0; ih < 2; ih++)
#pragma unroll
        for (int i = 0; i < 4; i++) {
            const int row = bm + ih * 64 + ty * 4 + i;
            const int ai = ih * 4 + i;
            float4 o0, o1;
            o0.x = acc[ai][0] + bb0.x; o0.y = acc[ai][1] + bb0.y;
            o0.z = acc[ai][2] + bb0.z; o0.w = acc[ai][3] + bb0.w;
            o1.x = acc[ai][4] + bb1.x; o1.y = acc[ai][5] + bb1.y;
            o1.z = acc[ai][6] + bb1.z; o1.w = acc[ai][7] + bb1.w;
            *(float4*)(C + (size_t)row * N + c0) = o0;
            *(float4*)(C + (size_t)row * N + c1) = o1;
        }
}

// ---------------------------------------------------------------------------
// Q projection at the last position only.
// ---------------------------------------------------------------------------
__global__ __launch_bounds__(256) void qlast_kernel(
    const float* __restrict__ h1, const float* __restrict__ wq,
    const float* __restrict__ bq, float* __restrict__ qout)
{
    const int b = blockIdx.x;
    const int t = threadIdx.x;
    __shared__ __align__(16) float hs[HID];
    hs[t] = h1[((size_t)b * SEQ + (SEQ - 1)) * HID + t];
    __syncthreads();
    const float4* wr = (const float4*)(wq + (size_t)t * HID);
    float acc = 0.0f;
#pragma unroll
    for (int k = 0; k < 64; k++) {
        const float4 wv = wr[k];
        const float4 hv = ((const float4*)hs)[k];
        acc += wv.x*hv.x + wv.y*hv.y + wv.z*hv.z + wv.w*hv.w;
    }
    qout[b * HID + t] = acc + bq[t];
}

// ---------------------------------------------------------------------------
// Decode attention at query S-1 with multiplicative decay on scores.
// ---------------------------------------------------------------------------
__global__ __launch_bounds__(256) void attn_kernel(
    const float* __restrict__ Kb, const float* __restrict__ Vb,
    const float* __restrict__ q, float* __restrict__ attn)
{
    const int b = blockIdx.x >> 2;
    const int h = blockIdx.x & 3;
    const int tid = threadIdx.x;

    __shared__ __align__(16) float qs[64];
    __shared__ float sc[SEQ];
    __shared__ float red[256];
    __shared__ float part[4][64];

    if (tid < 64) qs[tid] = q[b * HID + h * 64 + tid];
    __syncthreads();

    const float LN095 = -0.051293294387550533f;  // ln(0.95)
    for (int k = tid; k < SEQ; k += 256) {
        const float4* kr = (const float4*)(Kb + ((size_t)b * SEQ + k) * HID + h * 64);
        float acc = 0.0f;
#pragma unroll
        for (int d = 0; d < 16; d++) {
            const float4 kv = kr[d];
            const float4 qv = ((const float4*)qs)[d];
            acc += kv.x*qv.x + kv.y*qv.y + kv.z*qv.z + kv.w*qv.w;
        }
        const float dec = __expf(LN095 * (float)(SEQ - 1 - k));
        sc[k] = acc * 0.125f * dec;
    }
    __syncthreads();

    float m = -INFINITY;
    for (int k = tid; k < SEQ; k += 256) m = fmaxf(m, sc[k]);
    red[tid] = m;
    for (int off = 128; off > 0; off >>= 1) {
        __syncthreads();
        if (tid < off) red[tid] = fmaxf(red[tid], red[tid + off]);
    }
    __syncthreads();
    const float mx = red[0];

    float local = 0.0f;
    for (int k = tid; k < SEQ; k += 256) {
        const float p = expf(sc[k] - mx);
        sc[k] = p;
        local += p;
    }
    __syncthreads();
    red[tid] = local;
    for (int off = 128; off > 0; off >>= 1) {
        __syncthreads();
        if (tid < off) red[tid] += red[tid + off];
    }
    __syncthreads();
    const float total = red[0];

    const int chunk = tid >> 6;
    const int d = tid & 63;
    float acc = 0.0f;
    const int k0 = chunk * (SEQ / 4), k1 = (chunk + 1) * (SEQ / 4);
    for (int k = k0; k < k1; k++)
        acc += sc[k] * Vb[((size_t)b * SEQ + k) * HID + h * 64 + d];
    part[chunk][d] = acc;
    __syncthreads();
    if (tid < 64) {
        const float r = (part[0][tid] + part[1][tid]) + (part[2][tid] + part[3][tid]);
        attn[b * HID + h * 64 + tid] = r / total;
    }
}

// ---------------------------------------------------------------------------
// Head: context = attn @ wo^T + bo ; mean/log_var heads (5 each).
// ---------------------------------------------------------------------------
__global__ __launch_bounds__(256) void head_kernel(
    const float* __restrict__ attn, const float* __restrict__ wo,
    const float* __restrict__ bo, const float* __restrict__ w_mean,
    const float* __restrict__ b_mean, const float* __restrict__ w_var,
    const float* __restrict__ b_var, float* __restrict__ out)
{
    const int b = blockIdx.x;
    const int t = threadIdx.x;
    __shared__ __align__(16) float av[HID];
    __shared__ __align__(16) float ctx[HID];
    av[t] = attn[b * HID + t];
    __syncthreads();
    {
        const float4* wr = (const float4*)(wo + (size_t)t * HID);
        float acc = 0.0f;
#pragma unroll
        for (int k = 0; k < 64; k++) {
            const float4 wv = wr[k];
            const float4 hv = ((const float4*)av)[k];
            acc += wv.x*hv.x + wv.y*hv.y + wv.z*hv.z + wv.w*hv.w;
        }
        ctx[t] = acc + bo[t];
    }
    __syncthreads();
    if (t < 5) {
        const float4* wr = (const float4*)(w_mean + (size_t)t * HID);
        float acc = 0.0f;
#pragma unroll
        for (int k = 0; k < 64; k++) {
            const float4 wv = wr[k];
            const float4 hv = ((const float4*)ctx)[k];
            acc += wv.x*hv.x + wv.y*hv.y + wv.z*hv.z + wv.w*hv.w;
        }
        out[b * 5 + t] = acc + b_mean[t];
    } else if (t >= 8 && t < 13) {
        const int m = t - 8;
        const float4* wr = (const float4*)(w_var + (size_t)m * HID);
        float acc = 0.0f;
#pragma unroll
        for (int k = 0; k < 64; k++) {
            const float4 wv = wr[k];
            const float4 hv = ((const float4*)ctx)[k];
            acc += wv.x*hv.x + wv.y*hv.y + wv.z*hv.z + wv.w*hv.w;
        }
        out[BATCH * 5 + b * 5 + m] = acc + b_var[m];
    }
}

// ---------------------------------------------------------------------------
extern "C" void kernel_launch(void* const* d_in, const int* in_sizes, int n_in,
                              void* d_out, int out_size, void* d_ws, size_t ws_size,
                              hipStream_t stream) {
    const float* x      = (const float*)d_in[0];
    const float* w_ih0  = (const float*)d_in[1];
    const float* w_hh0  = (const float*)d_in[2];
    const float* b_ih0  = (const float*)d_in[3];
    const float* b_hh0  = (const float*)d_in[4];
    const float* w_ih1  = (const float*)d_in[5];
    const float* w_hh1  = (const float*)d_in[6];
    const float* b_ih1  = (const float*)d_in[7];
    const float* b_hh1  = (const float*)d_in[8];
    const float* wq     = (const float*)d_in[9];
    const float* bq     = (const float*)d_in[10];
    const float* wk     = (const float*)d_in[11];
    const float* bk     = (const float*)d_in[12];
    const float* wvv    = (const float*)d_in[13];
    const float* bv     = (const float*)d_in[14];
    const float* wo     = (const float*)d_in[15];
    const float* bo     = (const float*)d_in[16];
    const float* w_mean = (const float*)d_in[17];
    const float* b_mean = (const float*)d_in[18];
    const float* w_var  = (const float*)d_in[19];
    const float* b_var  = (const float*)d_in[20];
    float* out = (float*)d_out;

    // ws layout (bytes), ~54 MB peak:
    //  [0, 32M)        h0s tagged stream (fused) -> Kbuf|Vbuf after (32 MB)
    //  [32M, 36M)      xpr ring (fused)          -> qbuf|abuf after
    //  [36M, 36M+32K)  h1r parity ring (fused)
    //  [36M+32K, +16M) hbuf: plain h1 (fused writes; KV/qlast read)
    char* wsb = (char*)d_ws;
    u64*  h0s  = (u64*)(wsb);
    u64*  xpr  = (u64*)(wsb + 33554432);
    u64*  h1r  = (u64*)(wsb + 37748736);
    float* hbuf = (float*)(wsb + 37781504);
    float* Kbuf = (float*)(wsb);
    float* Vbuf = (float*)(wsb + 16777216);
    float* qbuf = (float*)(wsb + 33554432);
    float* abuf = (float*)(wsb + 33554432 + 8192);

    // 1. fused pipelined 2-layer LSTM (h1 -> hbuf)
    lstm_fused<<<96, 512, 0, stream>>>(x, w_ih0, w_hh0, b_ih0, b_hh0,
                                       w_ih1, w_hh1, b_ih1, b_hh1,
                                       h0s, xpr, h1r, hbuf);
    // 2. K and V projections (one launch)
    gemm_kv<<<dim3(128, 2, 2), 256, 0, stream>>>(hbuf, wk, bk, wvv, bv, Kbuf, Vbuf, 16384, 256, 256);
    // 3. Q at last position
    qlast_kernel<<<BATCH, 256, 0, stream>>>(hbuf, wq, bq, qbuf);
    // 4. decode attention with decay
    attn_kernel<<<BATCH * 4, 256, 0, stream>>>(Kbuf, Vbuf, qbuf, abuf);
    // 5. output proj + gaussian head
    head_kernel<<<BATCH, 256, 0, stream>>>(abuf, wo, bo, w_mean, b_mean, w_var, b_var, out);
}

// Round 5
// 3603.271 us; speedup vs baseline: 20.7351x; 1.0030x over previous
//
#include <hip/hip_runtime.h>
#include <math.h>

#define BATCH 8
#define SEQ   2048
#define IN    8
#define HID   256
#define G4    1024   // 4*HID
#define XPR_R 64     // xp ring depth (steps)

typedef unsigned long long u64;
typedef unsigned int u32;

__device__ __forceinline__ float sigmoidf_(float x) { return 1.0f / (1.0f + __expf(-x)); }
__device__ __forceinline__ float tanhf_(float x) { return 1.0f - 2.0f / (__expf(2.0f * x) + 1.0f); }
// padded LDS index for h: +4 words per 32 -> 8 distinct bank groups, conflict-free
__device__ __forceinline__ int hpad(int k) { return k + 4 * (k >> 5); }

// Light barrier: LDS-only drain. __syncthreads() emits s_waitcnt vmcnt(0)
// lgkmcnt(0) before s_barrier — the vmcnt(0) drains our fire-and-forget
// publish stores to L3 on the critical path EVERY step. No intra-block
// consumer needs those stores (cross-block consumers poll tags; each
// consume-before-barrier is enforced by load->ds_write data dependency,
// each publish-after-barrier by program order). So wait only on lgkmcnt.
__device__ __forceinline__ void light_barrier() {
    __asm__ volatile("s_waitcnt lgkmcnt(0)\n\ts_barrier" ::: "memory");
}

// Sum over the 8 lanes {base..base+7} (lane bits 0..2) using VALU DPP ops —
// keeps the reduce OFF the DS pipe. Butterfly: all 8 lanes end with the total.
__device__ __forceinline__ float dpp_add8(float v) {
    int x;
    x = __builtin_amdgcn_update_dpp(0, __float_as_int(v), 0xB1, 0xF, 0xF, false);  // quad_perm xor1
    v += __int_as_float(x);
    x = __builtin_amdgcn_update_dpp(0, __float_as_int(v), 0x4E, 0xF, 0xF, false);  // quad_perm xor2
    v += __int_as_float(x);
    x = __builtin_amdgcn_update_dpp(0, __float_as_int(v), 0x141, 0xF, 0xF, false); // row_half_mirror
    v += __int_as_float(x);
    return v;
}

// Tagged u64 word: {tag(s+1) << 32 | f32 bits}. Payload inside the atomic
// word -> RELAXED suffices (R3 lesson: acquire/release = L2-invalidate storm).
__device__ __forceinline__ float poll_tag(const u64* p, u32 tag) {
    u64 v;
    do { v = __hip_atomic_load(p, __ATOMIC_RELAXED, __HIP_MEMORY_SCOPE_AGENT); }
    while ((u32)(v >> 32) != tag);
    return __uint_as_float((u32)v);
}
__device__ __forceinline__ void pub_tag(u64* p, u32 tag, float x) {
    __hip_atomic_store(p, ((u64)tag << 32) | (u64)__float_as_uint(x),
                       __ATOMIC_RELAXED, __HIP_MEMORY_SCOPE_AGENT);
}

__device__ __forceinline__ void matvec8(const float4 (&w4)[4][8], const float* hrow, int ks,
                                        float& a0, float& a1, float& a2, float& a3) {
    a0 = a1 = a2 = a3 = 0.0f;
#pragma unroll
    for (int i = 0; i < 8; i++) {
        const float4 h4 = *(const float4*)(&hrow[36 * ks + 4 * i]);  // 8-lane broadcast
        a0 += w4[0][i].x*h4.x + w4[0][i].y*h4.y + w4[0][i].z*h4.z + w4[0][i].w*h4.w;
        a1 += w4[1][i].x*h4.x + w4[1][i].y*h4.y + w4[1][i].z*h4.z + w4[1][i].w*h4.w;
        a2 += w4[2][i].x*h4.x + w4[2][i].y*h4.y + w4[2][i].z*h4.z + w4[2][i].w*h4.w;
        a3 += w4[3][i].x*h4.x + w4[3][i].y*h4.y + w4[3][i].z*h4.z + w4[3][i].w*h4.w;
    }
}

// ---------------------------------------------------------------------------
// Fused pipelined 2-layer LSTM. Grid = 96 blocks x 512 threads:
//   bid&7 = batch b, bid>>3 = role: 0-3 L0 recurrence q; 4-7 P projection p;
//   8-11 L1 recurrence q.
// Dataflow: L0 -> h0 write-once tagged stream; P -> xp ring (64 steps,
// back-pressure from L1's parity ring); L1 -> parity ring + plain hbuf.
// Thread (rg=t>>3, ks=t&7) holds 4 rows x 32-col weight slice in 128 VGPRs.
// ---------------------------------------------------------------------------
__global__ __launch_bounds__(512, 2) void lstm_fused(
    const float* __restrict__ x,
    const float* __restrict__ w_ih0, const float* __restrict__ w_hh0,
    const float* __restrict__ b_ih0, const float* __restrict__ b_hh0,
    const float* __restrict__ w_ih1, const float* __restrict__ w_hh1,
    const float* __restrict__ b_ih1, const float* __restrict__ b_hh1,
    u64* __restrict__ h0s,    // [8][2048][256] tagged, write-once
    u64* __restrict__ xpr,    // [8][64][1024]  tagged ring
    u64* __restrict__ h1r,    // [2][8][256]    tagged parity ring
    float* __restrict__ hbuf) // [8][2048][256] plain h1
{
    const int bid = blockIdx.x;
    const int b    = bid & 7;
    const int role = bid >> 3;
    const int grp  = role >> 2;   // 0 L0, 1 P, 2 L1
    const int q    = role & 3;
    const int t    = threadIdx.x;
    const int ks   = t & 7;
    const int rg   = t >> 3;
    const int wv   = t >> 6;
    const int lane = t & 63;
    const bool isg = (ks == 0);

    __shared__ float h_lds[2][288];
    __shared__ float xbuf[2][256];   // L1: xp values, layout [gate j][unit] (conflict-free)

    u64* h0b = h0s + (size_t)b * SEQ * HID;
    u64* xpb = xpr + (size_t)b * XPR_R * G4;

    for (int i = t; i < 576; i += 512) ((float*)h_lds)[i] = 0.0f;
    __syncthreads();   // init must precede any pre-poll LDS write

    if (grp == 0) {
        // ================= L0: layer-0 recurrence, input proj fused =========
        float4 w4[4][8];
#pragma unroll
        for (int j = 0; j < 4; j++) {
            const float4* wr = (const float4*)(w_hh0 + (size_t)(256*j + 64*q + rg) * HID + ks * 32);
#pragma unroll
            for (int i = 0; i < 8; i++) w4[j][i] = wr[i];
        }
        float4 wi[4][2]; float bs4[4];
#pragma unroll
        for (int j = 0; j < 4; j++) {
            const int G = 256*j + 64*q + rg;
            wi[j][0] = *(const float4*)(w_ih0 + (size_t)G * IN);
            wi[j][1] = *(const float4*)(w_ih0 + (size_t)G * IN + 4);
            bs4[j] = b_ih0[G] + b_hh0[G];
        }
        const float* xb = x + (size_t)b * SEQ * IN;
        float c = 0.0f;
        float xv0 = 0, xv1 = 0, xv2 = 0, xv3 = 0;
        if (isg) {
            const float4 xa = *(const float4*)(xb);
            const float4 xc = *(const float4*)(xb + 4);
            xv0 = bs4[0] + wi[0][0].x*xa.x + wi[0][0].y*xa.y + wi[0][0].z*xa.z + wi[0][0].w*xa.w
                         + wi[0][1].x*xc.x + wi[0][1].y*xc.y + wi[0][1].z*xc.z + wi[0][1].w*xc.w;
            xv1 = bs4[1] + wi[1][0].x*xa.x + wi[1][0].y*xa.y + wi[1][0].z*xa.z + wi[1][0].w*xa.w
                         + wi[1][1].x*xc.x + wi[1][1].y*xc.y + wi[1][1].z*xc.z + wi[1][1].w*xc.w;
            xv2 = bs4[2] + wi[2][0].x*xa.x + wi[2][0].y*xa.y + wi[2][0].z*xa.z + wi[2][0].w*xa.w
                         + wi[2][1].x*xc.x + wi[2][1].y*xc.y + wi[2][1].z*xc.z + wi[2][1].w*xc.w;
            xv3 = bs4[3] + wi[3][0].x*xa.x + wi[3][0].y*xa.y + wi[3][0].z*xa.z + wi[3][0].w*xa.w
                         + wi[3][1].x*xc.x + wi[3][1].y*xc.y + wi[3][1].z*xc.z + wi[3][1].w*xc.w;
        }

        for (int s = 0; s < SEQ; s++) {
            const int cur = s & 1, nxt = cur ^ 1;
            float xn0 = 0, xn1 = 0, xn2 = 0, xn3 = 0;
            if (isg && s + 1 < SEQ) {
                const float4 xa = *(const float4*)(xb + (size_t)(s + 1) * IN);
                const float4 xc = *(const float4*)(xb + (size_t)(s + 1) * IN + 4);
                xn0 = bs4[0] + wi[0][0].x*xa.x + wi[0][0].y*xa.y + wi[0][0].z*xa.z + wi[0][0].w*xa.w
                             + wi[0][1].x*xc.x + wi[0][1].y*xc.y + wi[0][1].z*xc.z + wi[0][1].w*xc.w;
                xn1 = bs4[1] + wi[1][0].x*xa.x + wi[1][0].y*xa.y + wi[1][0].z*xa.z + wi[1][0].w*xa.w
                             + wi[1][1].x*xc.x + wi[1][1].y*xc.y + wi[1][1].z*xc.z + wi[1][1].w*xc.w;
                xn2 = bs4[2] + wi[2][0].x*xa.x + wi[2][0].y*xa.y + wi[2][0].z*xa.z + wi[2][0].w*xa.w
                             + wi[2][1].x*xc.x + wi[2][1].y*xc.y + wi[2][1].z*xc.z + wi[2][1].w*xc.w;
                xn3 = bs4[3] + wi[3][0].x*xa.x + wi[3][0].y*xa.y + wi[3][0].z*xa.z + wi[3][0].w*xa.w
                             + wi[3][1].x*xc.x + wi[3][1].y*xc.y + wi[3][1].z*xc.z + wi[3][1].w*xc.w;
            }
            float a0, a1, a2, a3;
            matvec8(w4, h_lds[cur], ks, a0, a1, a2, a3);
            a0 = dpp_add8(a0); a1 = dpp_add8(a1); a2 = dpp_add8(a2); a3 = dpp_add8(a3);
            const u32 tag = (u32)(s + 1);
            if (isg) {
                const float iv = sigmoidf_(a0 + xv0);
                const float fv = sigmoidf_(a1 + xv1);
                const float gv = tanhf_(a2 + xv2);
                const float ov = sigmoidf_(a3 + xv3);
                c = fv * c + iv * gv;
                const float hv = ov * tanhf_(c);
                const int u = 64*q + rg;
                h_lds[nxt][hpad(u)] = hv;
                pub_tag(&h0b[(size_t)s * HID + u], tag, hv);
                xv0 = xn0; xv1 = xn1; xv2 = xn2; xv3 = xn3;
            }
            if (wv >= 1 && wv <= 3) {
                const int u = 64 * ((q + wv) & 3) + lane;
                h_lds[nxt][hpad(u)] = poll_tag(&h0b[(size_t)s * HID + u], tag);
            }
            light_barrier();
        }
    } else if (grp == 1) {
        // ================= P: xp[s] = w_ih1 @ h0[s] + biases ================
        const int p = q;
        float4 w4[4][8]; float bs4[4];
#pragma unroll
        for (int j = 0; j < 4; j++) {
            const int R = 256*p + 64*j + rg;
            const float4* wr = (const float4*)(w_ih1 + (size_t)R * HID + ks * 32);
#pragma unroll
            for (int i = 0; i < 8; i++) w4[j][i] = wr[i];
            bs4[j] = b_ih1[R] + b_hh1[R];
        }
        if (wv >= 4) {   // pre-poll h0[0]
            const int u = 64 * (wv - 4) + lane;
            h_lds[0][hpad(u)] = poll_tag(&h0b[u], 1u);
        }
        __syncthreads();

        for (int s = 0; s < SEQ; s++) {
            const int cur = s & 1, nxt = cur ^ 1;
            float a0, a1, a2, a3;
            matvec8(w4, h_lds[cur], ks, a0, a1, a2, a3);
            a0 = dpp_add8(a0); a1 = dpp_add8(a1); a2 = dpp_add8(a2); a3 = dpp_add8(a3);
            const u32 tag = (u32)(s + 1);
            if (isg) {
                // ring back-pressure: xp slot s%64 may hold xp[s-64], consumed by
                // L1 during its step s-65; safe once a ring tag >= s-63 exists
                // (poison 0xAAAAAAAA filtered by <=2048).
                if (s >= XPR_R) {
                    const u32 need = (u32)(s - (XPR_R - 1));
                    const u64* bp = h1r + ((size_t)(need & 1u) * 8 + b) * HID + (64*p + rg);
                    u32 tt;
                    do { tt = (u32)(__hip_atomic_load(bp, __ATOMIC_RELAXED, __HIP_MEMORY_SCOPE_AGENT) >> 32); }
                    while (!(tt >= need && tt <= 2048u));
                }
                u64* slot = xpb + (size_t)(s & (XPR_R - 1)) * G4 + 256*p + rg;
                pub_tag(slot +   0, tag, a0 + bs4[0]);
                pub_tag(slot +  64, tag, a1 + bs4[1]);
                pub_tag(slot + 128, tag, a2 + bs4[2]);
                pub_tag(slot + 192, tag, a3 + bs4[3]);
            }
            if (wv >= 4 && s + 1 < SEQ) {   // prefetch h0[s+1]
                const int u = 64 * (wv - 4) + lane;
                h_lds[nxt][hpad(u)] = poll_tag(&h0b[(size_t)(s + 1) * HID + u], tag + 1u);
            }
            light_barrier();
        }
    } else {
        // ================= L1: layer-1 recurrence =========================
        float4 w4[4][8];
#pragma unroll
        for (int j = 0; j < 4; j++) {
            const float4* wr = (const float4*)(w_hh1 + (size_t)(256*j + 64*q + rg) * HID + ks * 32);
#pragma unroll
            for (int i = 0; i < 8; i++) w4[j][i] = wr[i];
        }
        float* ho = hbuf + (size_t)b * SEQ * HID;
        if (wv >= 4) {   // pre-poll xp[0]
            const int j = wv - 4;
            xbuf[0][64*j + lane] = poll_tag(&xpb[256*j + 64*q + lane], 1u);
        }
        __syncthreads();

        float c = 0.0f;
        for (int s = 0; s < SEQ; s++) {
            const int cur = s & 1, nxt = cur ^ 1;
            float a0, a1, a2, a3;
            matvec8(w4, h_lds[cur], ks, a0, a1, a2, a3);
            a0 = dpp_add8(a0); a1 = dpp_add8(a1); a2 = dpp_add8(a2); a3 = dpp_add8(a3);
            const u32 tag = (u32)(s + 1);
            if (isg) {
                const float xq0 = xbuf[cur][rg];
                const float xq1 = xbuf[cur][64 + rg];
                const float xq2 = xbuf[cur][128 + rg];
                const float xq3 = xbuf[cur][192 + rg];
                const float iv = sigmoidf_(a0 + xq0);
                const float fv = sigmoidf_(a1 + xq1);
                const float gv = tanhf_(a2 + xq2);
                const float ov = sigmoidf_(a3 + xq3);
                c = fv * c + iv * gv;
                const float hv = ov * tanhf_(c);
                const int u = 64*q + rg;
                h_lds[nxt][hpad(u)] = hv;
                ho[(size_t)s * HID + u] = hv;
                pub_tag(&h1r[((size_t)(tag & 1u) * 8 + b) * HID + u], tag, hv);
            }
            if (wv >= 1 && wv <= 3) {   // peer exchange (parity ring, lockstep)
                const int u = 64 * ((q + wv) & 3) + lane;
                h_lds[nxt][hpad(u)] = poll_tag(&h1r[((size_t)(tag & 1u) * 8 + b) * HID + u], tag);
            }
            if (wv >= 4 && s + 1 < SEQ) {   // prefetch xp[s+1]
                const int j = wv - 4;
                xbuf[nxt][64*j + lane] =
                    poll_tag(&xpb[(size_t)((s + 1) & (XPR_R - 1)) * G4 + 256*j + 64*q + lane], tag + 1u);
            }
            light_barrier();
        }
    }
}

// ---------------------------------------------------------------------------
// K and V projections in one launch (blockIdx.z selects). NT GEMM,
// 128x128x16 tiles, 256 threads, 8x8 micro-tile.
// ---------------------------------------------------------------------------
__global__ __launch_bounds__(256) void gemm_kv(
    const float* __restrict__ A,
    const float* __restrict__ Wk, const float* __restrict__ bk,
    const float* __restrict__ Wv, const float* __restrict__ bv,
    float* __restrict__ Ck, float* __restrict__ Cv, int M, int N, int K)
{
    const float* W    = blockIdx.z ? Wv : Wk;
    const float* bias = blockIdx.z ? bv : bk;
    float*       C    = blockIdx.z ? Cv : Ck;

    __shared__ float As[16][132];
    __shared__ float Bs[16][132];
    const int tid = threadIdx.x;
    const int tx = tid & 15;
    const int ty = tid >> 4;
    const int bm = blockIdx.x * 128;
    const int bn = blockIdx.y * 128;
    const int lrow = tid >> 1;
    const int lk = (tid & 1) * 8;

    float acc[8][8] = {};

    for (int k0 = 0; k0 < K; k0 += 16) {
        const float* ap = A + (size_t)(bm + lrow) * K + k0 + lk;
        const float* wp = W + (size_t)(bn + lrow) * K + k0 + lk;
        const float4 a0 = *(const float4*)ap;
        const float4 a1 = *(const float4*)(ap + 4);
        const float4 w0 = *(const float4*)wp;
        const float4 w1 = *(const float4*)(wp + 4);
        __syncthreads();
        As[lk+0][lrow] = a0.x; As[lk+1][lrow] = a0.y; As[lk+2][lrow] = a0.z; As[lk+3][lrow] = a0.w;
        As[lk+4][lrow] = a1.x; As[lk+5][lrow] = a1.y; As[lk+6][lrow] = a1.z; As[lk+7][lrow] = a1.w;
        Bs[lk+0][lrow] = w0.x; Bs[lk+1][lrow] = w0.y; Bs[lk+2][lrow] = w0.z; Bs[lk+3][lrow] = w0.w;
        Bs[lk+4][lrow] = w1.x; Bs[lk+5][lrow] = w1.y; Bs[lk+6][lrow] = w1.z; Bs[lk+7][lrow] = w1.w;
        __syncthreads();
#pragma unroll
        for (int k = 0; k < 16; k++) {
            const float4 av0 = *(const float4*)(&As[k][ty * 4]);
            const float4 av1 = *(const float4*)(&As[k][64 + ty * 4]);
            const float4 bv0 = *(const float4*)(&Bs[k][tx * 4]);
            const float4 bv1 = *(const float4*)(&Bs[k][64 + tx * 4]);
            const float ar[8] = {av0.x, av0.y, av0.z, av0.w, av1.x, av1.y, av1.z, av1.w};
            const float br[8] = {bv0.x, bv0.y, bv0.z, bv0.w, bv1.x, bv1.y, bv1.z, bv1.w};
#pragma unroll
            for (int i = 0; i < 8; i++)
#pragma unroll
                for (int j = 0; j < 8; j++) acc[i][j] += ar[i] * br[j];
        }
    }

    const int c0 = bn + tx * 4, c1 = bn + 64 + tx * 4;
    const float4 bb0 = *(const float4*)(bias + c0);
    const float4 bb1 = *(const float4*)(bias + c1);
#pragma unroll
    for (int ih = 0; ih < 2; ih++)
#pragma unroll
        for (int i = 0; i < 4; i++) {
            const int row = bm + ih * 64 + ty * 4 + i;
            const int ai = ih * 4 + i;
            float4 o0, o1;
            o0.x = acc[ai][0] + bb0.x; o0.y = acc[ai][1] + bb0.y;
            o0.z = acc[ai][2] + bb0.z; o0.w = acc[ai][3] + bb0.w;
            o1.x = acc[ai][4] + bb1.x; o1.y = acc[ai][5] + bb1.y;
            o1.z = acc[ai][6] + bb1.z; o1.w = acc[ai][7] + bb1.w;
            *(float4*)(C + (size_t)row * N + c0) = o0;
            *(float4*)(C + (size_t)row * N + c1) = o1;
        }
}

// ---------------------------------------------------------------------------
// Q projection at the last position only.
// ---------------------------------------------------------------------------
__global__ __launch_bounds__(256) void qlast_kernel(
    const float* __restrict__ h1, const float* __restrict__ wq,
    const float* __restrict__ bq, float* __restrict__ qout)
{
    const int b = blockIdx.x;
    const int t = threadIdx.x;
    __shared__ __align__(16) float hs[HID];
    hs[t] = h1[((size_t)b * SEQ + (SEQ - 1)) * HID + t];
    __syncthreads();
    const float4* wr = (const float4*)(wq + (size_t)t * HID);
    float acc = 0.0f;
#pragma unroll
    for (int k = 0; k < 64; k++) {
        const float4 wv = wr[k];
        const float4 hv = ((const float4*)hs)[k];
        acc += wv.x*hv.x + wv.y*hv.y + wv.z*hv.z + wv.w*hv.w;
    }
    qout[b * HID + t] = acc + bq[t];
}

// ---------------------------------------------------------------------------
// Decode attention at query S-1 with multiplicative decay on scores.
// ---------------------------------------------------------------------------
__global__ __launch_bounds__(256) void attn_kernel(
    const float* __restrict__ Kb, const float* __restrict__ Vb,
    const float* __restrict__ q, float* __restrict__ attn)
{
    const int b = blockIdx.x >> 2;
    const int h = blockIdx.x & 3;
    const int tid = threadIdx.x;

    __shared__ __align__(16) float qs[64];
    __shared__ float sc[SEQ];
    __shared__ float red[256];
    __shared__ float part[4][64];

    if (tid < 64) qs[tid] = q[b * HID + h * 64 + tid];
    __syncthreads();

    const float LN095 = -0.051293294387550533f;  // ln(0.95)
    for (int k = tid; k < SEQ; k += 256) {
        const float4* kr = (const float4*)(Kb + ((size_t)b * SEQ + k) * HID + h * 64);
        float acc = 0.0f;
#pragma unroll
        for (int d = 0; d < 16; d++) {
            const float4 kv = kr[d];
            const float4 qv = ((const float4*)qs)[d];
            acc += kv.x*qv.x + kv.y*qv.y + kv.z*qv.z + kv.w*qv.w;
        }
        const float dec = __expf(LN095 * (float)(SEQ - 1 - k));
        sc[k] = acc * 0.125f * dec;
    }
    __syncthreads();

    float m = -INFINITY;
    for (int k = tid; k < SEQ; k += 256) m = fmaxf(m, sc[k]);
    red[tid] = m;
    for (int off = 128; off > 0; off >>= 1) {
        __syncthreads();
        if (tid < off) red[tid] = fmaxf(red[tid], red[tid + off]);
    }
    __syncthreads();
    const float mx = red[0];

    float local = 0.0f;
    for (int k = tid; k < SEQ; k += 256) {
        const float p = expf(sc[k] - mx);
        sc[k] = p;
        local += p;
    }
    __syncthreads();
    red[tid] = local;
    for (int off = 128; off > 0; off >>= 1) {
        __syncthreads();
        if (tid < off) red[tid] += red[tid + off];
    }
    __syncthreads();
    const float total = red[0];

    const int chunk = tid >> 6;
    const int d = tid & 63;
    float acc = 0.0f;
    const int k0 = chunk * (SEQ / 4), k1 = (chunk + 1) * (SEQ / 4);
    for (int k = k0; k < k1; k++)
        acc += sc[k] * Vb[((size_t)b * SEQ + k) * HID + h * 64 + d];
    part[chunk][d] = acc;
    __syncthreads();
    if (tid < 64) {
        const float r = (part[0][tid] + part[1][tid]) + (part[2][tid] + part[3][tid]);
        attn[b * HID + h * 64 + tid] = r / total;
    }
}

// ---------------------------------------------------------------------------
// Head: context = attn @ wo^T + bo ; mean/log_var heads (5 each).
// ---------------------------------------------------------------------------
__global__ __launch_bounds__(256) void head_kernel(
    const float* __restrict__ attn, const float* __restrict__ wo,
    const float* __restrict__ bo, const float* __restrict__ w_mean,
    const float* __restrict__ b_mean, const float* __restrict__ w_var,
    const float* __restrict__ b_var, float* __restrict__ out)
{
    const int b = blockIdx.x;
    const int t = threadIdx.x;
    __shared__ __align__(16) float av[HID];
    __shared__ __align__(16) float ctx[HID];
    av[t] = attn[b * HID + t];
    __syncthreads();
    {
        const float4* wr = (const float4*)(wo + (size_t)t * HID);
        float acc = 0.0f;
#pragma unroll
        for (int k = 0; k < 64; k++) {
            const float4 wv = wr[k];
            const float4 hv = ((const float4*)av)[k];
            acc += wv.x*hv.x + wv.y*hv.y + wv.z*hv.z + wv.w*hv.w;
        }
        ctx[t] = acc + bo[t];
    }
    __syncthreads();
    if (t < 5) {
        const float4* wr = (const float4*)(w_mean + (size_t)t * HID);
        float acc = 0.0f;
#pragma unroll
        for (int k = 0; k < 64; k++) {
            const float4 wv = wr[k];
            const float4 hv = ((const float4*)ctx)[k];
            acc += wv.x*hv.x + wv.y*hv.y + wv.z*hv.z + wv.w*hv.w;
        }
        out[b * 5 + t] = acc + b_mean[t];
    } else if (t >= 8 && t < 13) {
        const int m = t - 8;
        const float4* wr = (const float4*)(w_var + (size_t)m * HID);
        float acc = 0.0f;
#pragma unroll
        for (int k = 0; k < 64; k++) {
            const float4 wv = wr[k];
            const float4 hv = ((const float4*)ctx)[k];
            acc += wv.x*hv.x + wv.y*hv.y + wv.z*hv.z + wv.w*hv.w;
        }
        out[BATCH * 5 + b * 5 + m] = acc + b_var[m];
    }
}

// ---------------------------------------------------------------------------
extern "C" void kernel_launch(void* const* d_in, const int* in_sizes, int n_in,
                              void* d_out, int out_size, void* d_ws, size_t ws_size,
                              hipStream_t stream) {
    const float* x      = (const float*)d_in[0];
    const float* w_ih0  = (const float*)d_in[1];
    const float* w_hh0  = (const float*)d_in[2];
    const float* b_ih0  = (const float*)d_in[3];
    const float* b_hh0  = (const float*)d_in[4];
    const float* w_ih1  = (const float*)d_in[5];
    const float* w_hh1  = (const float*)d_in[6];
    const float* b_ih1  = (const float*)d_in[7];
    const float* b_hh1  = (const float*)d_in[8];
    const float* wq     = (const float*)d_in[9];
    const float* bq     = (const float*)d_in[10];
    const float* wk     = (const float*)d_in[11];
    const float* bk     = (const float*)d_in[12];
    const float* wvv    = (const float*)d_in[13];
    const float* bv     = (const float*)d_in[14];
    const float* wo     = (const float*)d_in[15];
    const float* bo     = (const float*)d_in[16];
    const float* w_mean = (const float*)d_in[17];
    const float* b_mean = (const float*)d_in[18];
    const float* w_var  = (const float*)d_in[19];
    const float* b_var  = (const float*)d_in[20];
    float* out = (float*)d_out;

    // ws layout (bytes), ~54 MB peak:
    //  [0, 32M)        h0s tagged stream (fused) -> Kbuf|Vbuf after (32 MB)
    //  [32M, 36M)      xpr ring (fused)          -> qbuf|abuf after
    //  [36M, 36M+32K)  h1r parity ring (fused)
    //  [36M+32K, +16M) hbuf: plain h1 (fused writes; KV/qlast read)
    char* wsb = (char*)d_ws;
    u64*  h0s  = (u64*)(wsb);
    u64*  xpr  = (u64*)(wsb + 33554432);
    u64*  h1r  = (u64*)(wsb + 37748736);
    float* hbuf = (float*)(wsb + 37781504);
    float* Kbuf = (float*)(wsb);
    float* Vbuf = (float*)(wsb + 16777216);
    float* qbuf = (float*)(wsb + 33554432);
    float* abuf = (float*)(wsb + 33554432 + 8192);

    // 1. fused pipelined 2-layer LSTM (h1 -> hbuf)
    lstm_fused<<<96, 512, 0, stream>>>(x, w_ih0, w_hh0, b_ih0, b_hh0,
                                       w_ih1, w_hh1, b_ih1, b_hh1,
                                       h0s, xpr, h1r, hbuf);
    // 2. K and V projections (one launch)
    gemm_kv<<<dim3(128, 2, 2), 256, 0, stream>>>(hbuf, wk, bk, wvv, bv, Kbuf, Vbuf, 16384, 256, 256);
    // 3. Q at last position
    qlast_kernel<<<BATCH, 256, 0, stream>>>(hbuf, wq, bq, qbuf);
    // 4. decode attention with decay
    attn_kernel<<<BATCH * 4, 256, 0, stream>>>(Kbuf, Vbuf, qbuf, abuf);
    // 5. output proj + gaussian head
    head_kernel<<<BATCH, 256, 0, stream>>>(abuf, wo, bo, w_mean, b_mean, w_var, b_var, out);
}